// Round 7
// baseline (6021.152 us; speedup 1.0000x reference)
//
#include <hip/hip_runtime.h>
#include <math.h>

#define NWALK 32000
#define NNODE 8000
#define NEDGE 64000

// workspace layout (float offsets)
static const size_t OFF_WT   = 0;                          // 5 k-major 64x192 mats: wf,wb,m,A,B
static const size_t OFF_TF   = OFF_WT + 5*12288;           // T_f[8][192]
static const size_t OFF_TB   = OFF_TF + 1536;              // T_b[8][192]
static const size_t OFF_ME   = OFF_TB + 1536;              // M_edge[192][16]
static const size_t OFF_WMHT = OFF_ME + 3072;              // WmhT[64][192]
static const size_t OFF_WDEG = OFF_WMHT + 12288;           // wdeg[192]
static const size_t OFF_DMAX = OFF_WDEG + 192;             // int degmax (+pad)
static const size_t OFF_E2   = OFF_DMAX + 64;              // E2[64000][192]
static const size_t OFF_H2   = OFF_E2 + (size_t)NEDGE*192; // H2[8000][192]
static const size_t OFF_XGE  = OFF_H2 + (size_t)NNODE*192; // XGE[32000][8][192]
static const size_t OFF_HW   = OFF_XGE + (size_t)NWALK*8*192; // HW[32000][64]

__device__ __forceinline__ float sigm(float x){ return 1.f/(1.f+__expf(-x)); }
__device__ __forceinline__ float tanh_(float x){ float e=__expf(2.f*x); return 1.f-2.f/(e+1.f); }

__global__ void k_init(int* dmax){ if (threadIdx.x==0) *dmax = 0; }

// k-major transposes: WT[m][k][g]
__global__ void k_prep_wt(const float* __restrict__ whh_wf, const float* __restrict__ whh_wb,
                          const float* __restrict__ whh_m,  const float* __restrict__ wih_m,
                          float* __restrict__ WT){
  int idx = blockIdx.x*256 + threadIdx.x;
  if (idx >= 5*12288) return;
  int m = idx / 12288, r = idx % 12288;
  int k = r / 192, g = r % 192;
  float v;
  if      (m==0) v = whh_wf[g*64+k];
  else if (m==1) v = whh_wb[g*64+k];
  else if (m==2) v = whh_m [g*64+k];
  else if (m==3) v = wih_m [g*193 + 64  + k];   // A = Wih_m[:,64:128]
  else           v = wih_m [g*193 + 128 + k];   // B = Wih_m[:,128:192]
  WT[m*12288 + k*192 + g] = v;
}

__global__ void k_prep_tbl(const float* __restrict__ wih_wf, const float* __restrict__ bih_wf,
                           const float* __restrict__ wih_wb, const float* __restrict__ bih_wb,
                           float* __restrict__ Tf, float* __restrict__ Tb){
  int idx = blockIdx.x*256+threadIdx.x;
  if (idx >= 3072) return;
  int which = idx / 1536, r = idx % 1536;
  int u = r / 192, g = r % 192;
  float ang = (float)u * 0.78539816339744831f; // pi/4
  float s = sinf(ang), c = cosf(ang);
  if (which==0) Tf[u*192+g] = bih_wf[g] + wih_wf[g*2+0]*s + wih_wf[g*2+1]*c;
  else          Tb[u*192+g] = bih_wb[g] + wih_wb[g*2+0]*s + wih_wb[g*2+1]*c;
}

__global__ void k_prep_misc(const float* __restrict__ wih_m, const float* __restrict__ w_edge,
                            float* __restrict__ M, float* __restrict__ WmhT,
                            float* __restrict__ wdeg){
  int idx = blockIdx.x*256+threadIdx.x;
  if (idx < 3072){
    int g = idx >> 4, f = idx & 15;
    float acc = 0.f;
    for (int d=0; d<193; ++d) acc += wih_m[g*193+d]*w_edge[d*16+f];
    M[g*16+f] = acc;
  }
  int j = idx - 3072;
  if (j >= 0 && j < 12288){
    int k = j / 192, g = j % 192;
    WmhT[k*192+g] = wih_m[g*193+k];
  }
  int q = idx - 3072 - 12288;
  if (q >= 0 && q < 192) wdeg[q] = wih_m[q*193+192];
}

__global__ void k_degmax(const int* __restrict__ walks, const int* __restrict__ degs,
                         int* __restrict__ dmax){
  int idx = blockIdx.x*256+threadIdx.x;
  int v = 0;
  if (idx < NWALK*8) v = degs[walks[idx]];
  #pragma unroll
  for (int off=32; off; off>>=1) v = max(v, __shfl_xor(v, off));
  if ((threadIdx.x & 63)==0) atomicMax(dmax, v);
}

__global__ void k_e2(const float* __restrict__ e, const float* __restrict__ M,
                     const float* __restrict__ bih_m, float* __restrict__ E2){
  int edge = blockIdx.x;
  int g = threadIdx.x;
  __shared__ float ev[16];
  if (g < 16) ev[g] = e[edge*16+g];
  __syncthreads();
  float acc = bih_m[g];
  #pragma unroll
  for (int f=0; f<16; ++f) acc += ev[f]*M[g*16+f];
  E2[(size_t)edge*192+g] = acc;
}

__global__ void k_h2(const float* __restrict__ h, const float* __restrict__ WmhT,
                     float* __restrict__ H2){
  int node = blockIdx.x; int g = threadIdx.x;
  __shared__ float hv[64];
  if (g < 64) hv[g] = h[node*64+g];
  __syncthreads();
  float acc = 0.f;
  for (int k=0;k<64;++k) acc += hv[k]*WmhT[k*192+g];
  H2[(size_t)node*192+g] = acc;
}

// ---------------------------------------------------------------------------
// thread = walk. Weights indexed uniformly across the wave -> scalar (s_load)
// path; h state in a private LDS row per thread (padded to 65 floats ->
// conflict-free); ping-pong buffers; NO barriers, no inter-thread sharing.
// dirb=0: forward GRU, projection A^T y + H2 + deg + bias -> XGE (write)
// dirb=1: backward GRU, XGE += B^T y (RMW; ordered by separate launch)
// ---------------------------------------------------------------------------
__global__ __launch_bounds__(128,1) void k_walkg(
    const int* __restrict__ walks, const int* __restrict__ degs,
    const int* __restrict__ dmaxp,
    const float* __restrict__ WT,   // rec weights, k-major [64][192]
    const float* __restrict__ PT,   // proj weights, k-major [64][192]
    const float* __restrict__ TB,   // x-table [8][192] (incl bih)
    const float* __restrict__ bhh,  // [192]
    const float* __restrict__ H2,
    const float* __restrict__ wdeg,
    const float* __restrict__ bihm,
    float* __restrict__ XGE, float* __restrict__ HW,
    const int dirb)
{
  __shared__ float hls[2][128][65];
  const int tid = threadIdx.x;
  const int v = blockIdx.x*128 + tid;
  const float inv_dmax = 1.0f/(float)(*dmaxp);
  int cur = 0;
  for (int q=0;q<8;++q){
    const int p = dirb ? 7-q : q;   // GRU position within sequence
    const int i = 7-p;              // original (unreversed) walk index
    const int wi = walks[v*8+i];
    int u = i;                      // first occurrence of walks[i] in walk
    #pragma unroll
    for (int j=7;j>=0;--j){ if (j<=i && walks[v*8+j]==wi) u=j; }

    // --- recurrent matvec + gates, 4 hidden units per chunk ---
    #pragma unroll 1
    for (int j0=0;j0<64;j0+=4){
      float ar[4],az[4],an_[4];
      #pragma unroll
      for (int jj=0;jj<4;++jj){
        ar[jj]=bhh[j0+jj]; az[jj]=bhh[64+j0+jj]; an_[jj]=bhh[128+j0+jj];
      }
      if (q>0){
        #pragma unroll
        for (int k=0;k<64;++k){
          const float hk = hls[cur][tid][k];
          #pragma unroll
          for (int jj=0;jj<4;++jj){
            ar[jj]  += WT[k*192 +       j0+jj]*hk;
            az[jj]  += WT[k*192 + 64  + j0+jj]*hk;
            an_[jj] += WT[k*192 + 128 + j0+jj]*hk;
          }
        }
      }
      #pragma unroll
      for (int jj=0;jj<4;++jj){
        const int j = j0+jj;
        const float xr = TB[u*192+j], xz = TB[u*192+64+j], xn = TB[u*192+128+j];
        const float r = sigm(xr+ar[jj]);
        const float z = sigm(xz+az[jj]);
        const float n = tanh_(xn + r*an_[jj]);
        const float hold = (q>0) ? hls[cur][tid][j] : 0.f;
        hls[cur^1][tid][j] = (1.f-z)*n + z*hold;
      }
    }
    cur ^= 1;

    // --- projection of y=h_new into XGE row p ---
    const size_t row = ((size_t)v*8 + p)*192;
    const float dd = (float)degs[wi]*inv_dmax;
    #pragma unroll 1
    for (int g0=0;g0<192;g0+=12){
      float ac[12];
      if (dirb==0){
        #pragma unroll
        for (int gg=0;gg<12;++gg)
          ac[gg] = H2[(size_t)wi*192 + g0+gg] + dd*wdeg[g0+gg] + bihm[g0+gg];
      } else {
        #pragma unroll
        for (int gg=0;gg<12;++gg) ac[gg] = XGE[row + g0+gg];
      }
      #pragma unroll
      for (int k=0;k<64;++k){
        const float yk = hls[cur][tid][k];
        #pragma unroll
        for (int gg=0;gg<12;++gg) ac[gg] += PT[k*192 + g0+gg]*yk;
      }
      #pragma unroll
      for (int gg=0;gg<12;++gg) XGE[row + g0+gg] = ac[gg];
    }
  }
  // h_walk = 0.5*(hf+hb): f writes, b accumulates
  if (dirb==0){
    #pragma unroll 1
    for (int k=0;k<64;++k) HW[(size_t)v*64+k] = 0.5f*hls[cur][tid][k];
  } else {
    #pragma unroll 1
    for (int k=0;k<64;++k) HW[(size_t)v*64+k] += 0.5f*hls[cur][tid][k];
  }
}

__global__ __launch_bounds__(128,1) void k_maing(
    const int* __restrict__ eids, const float* __restrict__ bhh,
    const float* __restrict__ WT, const float* __restrict__ XGE,
    const float* __restrict__ E2, const float* __restrict__ HW,
    float* __restrict__ out)
{
  __shared__ float hls[2][128][65];
  const int tid = threadIdx.x;
  const int v = blockIdx.x*128 + tid;
  #pragma unroll 1
  for (int k=0;k<64;++k) hls[0][tid][k] = HW[(size_t)v*64+k];
  int cur = 0;
  for (int t=0;t<15;++t){
    const float* xg = (t&1) ? (E2  + (size_t)eids[v*7+(t>>1)]*192)
                            : (XGE + ((size_t)v*8 + (t>>1))*192);
    #pragma unroll 1
    for (int j0=0;j0<64;j0+=4){
      float ar[4],az[4],an_[4];
      #pragma unroll
      for (int jj=0;jj<4;++jj){
        ar[jj]=bhh[j0+jj]; az[jj]=bhh[64+j0+jj]; an_[jj]=bhh[128+j0+jj];
      }
      #pragma unroll
      for (int k=0;k<64;++k){
        const float hk = hls[cur][tid][k];
        #pragma unroll
        for (int jj=0;jj<4;++jj){
          ar[jj]  += WT[k*192 +       j0+jj]*hk;
          az[jj]  += WT[k*192 + 64  + j0+jj]*hk;
          an_[jj] += WT[k*192 + 128 + j0+jj]*hk;
        }
      }
      #pragma unroll
      for (int jj=0;jj<4;++jj){
        const int j = j0+jj;
        const float r = sigm(xg[j]      + ar[jj]);
        const float z = sigm(xg[64+j]   + az[jj]);
        const float n = tanh_(xg[128+j] + r*an_[jj]);
        hls[cur^1][tid][j] = (1.f-z)*n + z*hls[cur][tid][j];
      }
    }
    cur ^= 1;
  }
  #pragma unroll 1
  for (int k=0;k<64;++k) out[(size_t)v*64+k] = hls[cur][tid][k];
}

extern "C" void kernel_launch(void* const* d_in, const int* in_sizes, int n_in,
                              void* d_out, int out_size, void* d_ws, size_t ws_size,
                              hipStream_t stream)
{
  const float* h      = (const float*)d_in[0];
  const float* e      = (const float*)d_in[2];
  const int*   walks  = (const int*)d_in[3];
  const int*   eids   = (const int*)d_in[4];
  const int*   degs   = (const int*)d_in[5];
  const float* wih_wf = (const float*)d_in[6];
  const float* whh_wf = (const float*)d_in[7];
  const float* bih_wf = (const float*)d_in[8];
  const float* bhh_wf = (const float*)d_in[9];
  const float* wih_wb = (const float*)d_in[10];
  const float* whh_wb = (const float*)d_in[11];
  const float* bih_wb = (const float*)d_in[12];
  const float* bhh_wb = (const float*)d_in[13];
  const float* wih_m  = (const float*)d_in[14];
  const float* whh_m  = (const float*)d_in[15];
  const float* bih_m  = (const float*)d_in[16];
  const float* bhh_m  = (const float*)d_in[17];
  const float* w_edge = (const float*)d_in[18];
  float* out = (float*)d_out;
  float* wsf = (float*)d_ws;

  float* WT   = wsf + OFF_WT;
  float* Tf   = wsf + OFF_TF;
  float* Tb   = wsf + OFF_TB;
  float* Me   = wsf + OFF_ME;
  float* WmhT = wsf + OFF_WMHT;
  float* wdeg = wsf + OFF_WDEG;
  int*   dmax = (int*)(wsf + OFF_DMAX);
  float* E2   = wsf + OFF_E2;
  float* H2   = wsf + OFF_H2;
  float* XGE  = wsf + OFF_XGE;
  float* HW   = wsf + OFF_HW;

  hipLaunchKernelGGL(k_init,      dim3(1),    dim3(64), 0, stream, dmax);
  hipLaunchKernelGGL(k_prep_wt,   dim3(240),  dim3(256),0, stream, whh_wf,whh_wb,whh_m,wih_m,WT);
  hipLaunchKernelGGL(k_prep_tbl,  dim3(12),   dim3(256),0, stream, wih_wf,bih_wf,wih_wb,bih_wb,Tf,Tb);
  hipLaunchKernelGGL(k_prep_misc, dim3(61),   dim3(256),0, stream, wih_m,w_edge,Me,WmhT,wdeg);
  hipLaunchKernelGGL(k_degmax,    dim3(1000), dim3(256),0, stream, walks,degs,dmax);
  hipLaunchKernelGGL(k_e2,        dim3(NEDGE),dim3(192),0, stream, e,Me,bih_m,E2);
  hipLaunchKernelGGL(k_h2,        dim3(NNODE),dim3(192),0, stream, h,WmhT,H2);
  // forward walk GRU (writes XGE, HW)
  hipLaunchKernelGGL(k_walkg,     dim3(250),  dim3(128),0, stream,
                     walks,degs,dmax, WT+0*12288, WT+3*12288, Tf, bhh_wf,
                     H2,wdeg,bih_m, XGE,HW, 0);
  // backward walk GRU (RMW XGE, HW) — ordered after forward by stream
  hipLaunchKernelGGL(k_walkg,     dim3(250),  dim3(128),0, stream,
                     walks,degs,dmax, WT+1*12288, WT+4*12288, Tb, bhh_wb,
                     H2,wdeg,bih_m, XGE,HW, 1);
  hipLaunchKernelGGL(k_maing,     dim3(250),  dim3(128),0, stream,
                     eids,bhh_m, WT+2*12288, XGE,E2,HW, out);
  (void)in_sizes;(void)n_in;(void)out_size;(void)ws_size;
}

// Round 8
// 984.526 us; speedup vs baseline: 6.1158x; 6.1158x over previous
//
#include <hip/hip_runtime.h>
#include <math.h>

#define NWALK 32000
#define NNODE 8000
#define NEDGE 64000

// workspace layout (float offsets)
static const size_t OFF_WL   = 0;                          // 5 chunked 192x64 mats: wf,wb,m,A,B
static const size_t OFF_TF   = OFF_WL + 5*12288;           // T_f[8][192]
static const size_t OFF_TB   = OFF_TF + 1536;              // T_b[8][192]
static const size_t OFF_ME   = OFF_TB + 1536;              // M_edge[192][16]
static const size_t OFF_WMHT = OFF_ME + 3072;              // WmhT[64][192]
static const size_t OFF_WDEG = OFF_WMHT + 12288;           // wdeg[192]
static const size_t OFF_DMAX = OFF_WDEG + 192;             // int degmax (+pad)
static const size_t OFF_E2   = OFF_DMAX + 64;              // E2[64000][192]
static const size_t OFF_H2   = OFF_E2 + (size_t)NEDGE*192; // H2[8000][192]
static const size_t OFF_XGE  = OFF_H2 + (size_t)NNODE*192; // XGE[256000][192]
static const size_t OFF_HW   = OFF_XGE + (size_t)NWALK*8*192; // HW[32000][64]
static const size_t OFF_MND  = OFF_HW + (size_t)NWALK*64;  // M_node[256000] (int)
static const size_t OFF_MDD  = OFF_MND + (size_t)NWALK*8;  // M_dd[256000]

__device__ __forceinline__ float sigm(float x){ return 1.f/(1.f+__expf(-x)); }
__device__ __forceinline__ float tanh_(float x){ float e=__expf(2.f*x); return 1.f-2.f/(e+1.f); }

__global__ void k_init(int* dmax){ if (threadIdx.x==0) *dmax = 0; }

// chunked layout for MM3: dst[(k>>2)*768 + g*4 + (k&3)]
__global__ void k_prep_wl(const float* __restrict__ whh_wf, const float* __restrict__ whh_wb,
                          const float* __restrict__ whh_m,  const float* __restrict__ wih_m,
                          float* __restrict__ WL){
  int idx = blockIdx.x*256 + threadIdx.x;
  if (idx >= 5*12288) return;
  int m = idx / 12288, r = idx % 12288;
  int g = r >> 6, k = r & 63;
  float v;
  if      (m==0) v = whh_wf[g*64+k];
  else if (m==1) v = whh_wb[g*64+k];
  else if (m==2) v = whh_m [g*64+k];
  else if (m==3) v = wih_m [g*193 + 64  + k];   // A
  else           v = wih_m [g*193 + 128 + k];   // B
  WL[m*12288 + (k>>2)*768 + g*4 + (k&3)] = v;
}

__global__ void k_prep_tbl(const float* __restrict__ wih_wf, const float* __restrict__ bih_wf,
                           const float* __restrict__ wih_wb, const float* __restrict__ bih_wb,
                           float* __restrict__ Tf, float* __restrict__ Tb){
  int idx = blockIdx.x*256+threadIdx.x;
  if (idx >= 3072) return;
  int which = idx / 1536, r = idx % 1536;
  int u = r / 192, g = r % 192;
  float ang = (float)u * 0.78539816339744831f; // pi/4
  float s = sinf(ang), c = cosf(ang);
  if (which==0) Tf[u*192+g] = bih_wf[g] + wih_wf[g*2+0]*s + wih_wf[g*2+1]*c;
  else          Tb[u*192+g] = bih_wb[g] + wih_wb[g*2+0]*s + wih_wb[g*2+1]*c;
}

__global__ void k_prep_misc(const float* __restrict__ wih_m, const float* __restrict__ w_edge,
                            float* __restrict__ M, float* __restrict__ WmhT,
                            float* __restrict__ wdeg){
  int idx = blockIdx.x*256+threadIdx.x;
  if (idx < 3072){
    int g = idx >> 4, f = idx & 15;
    float acc = 0.f;
    for (int d=0; d<193; ++d) acc += wih_m[g*193+d]*w_edge[d*16+f];
    M[g*16+f] = acc;
  }
  int j = idx - 3072;
  if (j >= 0 && j < 12288){
    int k = j / 192, g = j % 192;
    WmhT[k*192+g] = wih_m[g*193+k];
  }
  int q = idx - 3072 - 12288;
  if (q >= 0 && q < 192) wdeg[q] = wih_m[q*193+192];
}

__global__ void k_degmax(const int* __restrict__ walks, const int* __restrict__ degs,
                         int* __restrict__ dmax){
  int idx = blockIdx.x*256+threadIdx.x;
  int v = 0;
  if (idx < NWALK*8) v = degs[walks[idx]];
  #pragma unroll
  for (int off=32; off; off>>=1) v = max(v, __shfl_xor(v, off));
  if ((threadIdx.x & 63)==0) atomicMax(dmax, v);
}

__global__ void k_e2(const float* __restrict__ e, const float* __restrict__ M,
                     const float* __restrict__ bih_m, float* __restrict__ E2){
  int edge = blockIdx.x;
  int g = threadIdx.x;
  __shared__ float ev[16];
  if (g < 16) ev[g] = e[edge*16+g];
  __syncthreads();
  float acc = bih_m[g];
  #pragma unroll
  for (int f=0; f<16; ++f) acc += ev[f]*M[g*16+f];
  E2[(size_t)edge*192+g] = acc;
}

__global__ void k_h2(const float* __restrict__ h, const float* __restrict__ WmhT,
                     float* __restrict__ H2){
  int node = blockIdx.x; int g = threadIdx.x;
  __shared__ float hv[64];
  if (g < 64) hv[g] = h[node*64+g];
  __syncthreads();
  float acc = 0.f;
  for (int k=0;k<64;++k) acc += hv[k]*WmhT[k*192+g];
  H2[(size_t)node*192+g] = acc;
}

#define DOT4(a,b) ((a).x*(b).x+(a).y*(b).y+(a).z*(b).z+(a).w*(b).w)
// 3-gate matvec, 8 walks/wave. unroll 2: cap live weight-load registers.
#define MM3_8(W4, HPTR, A0, A1, A2) do { \
  _Pragma("unroll 2") \
  for (int c=0;c<16;++c){ \
    float4 w0=(W4)[c*192+lane]; \
    float4 w1=(W4)[c*192+64+lane]; \
    float4 w2=(W4)[c*192+128+lane]; \
    _Pragma("unroll") \
    for (int w=0;w<8;++w){ \
      float4 hv=*(const float4*)(HPTR(w)+c*4); \
      A0[w]+=DOT4(w0,hv); A1[w]+=DOT4(w1,hv); A2[w]+=DOT4(w2,hv); } } \
} while(0)

// recurrent-only walk GRU (8 walks/wave, 64 walks/block); y -> XGE col range
__global__ __launch_bounds__(512,2) void k_wgru(
    const int* __restrict__ walks, const int* __restrict__ degs,
    const int* __restrict__ dmaxp,
    const float* __restrict__ WLb,   // chunked rec weights (this dir)
    const float* __restrict__ TBL,   // x-table [8][192] (incl bih)
    const float* __restrict__ bhh,   // [192]
    float* __restrict__ XGE, float* __restrict__ HW,
    int* __restrict__ M_node, float* __restrict__ M_dd,
    const int dirb)
{
  __shared__ __align__(16) float wrec[12288];
  __shared__ __align__(16) float hbuf[64][64];
  __shared__ __align__(16) float tbl[1536];
  __shared__ float sb_bhh[192];
  __shared__ int   m_u[64][8];

  const int tid = threadIdx.x;
  const int wave = tid>>6, lane = tid&63;
  const int wkb = wave<<3;
  const int vbase = blockIdx.x*64;

  for (int i=tid;i<3072;i+=512) ((float4*)wrec)[i]=((const float4*)WLb)[i];
  for (int i=tid;i<1536;i+=512) tbl[i]=TBL[i];
  if (tid<192) sb_bhh[tid]=bhh[tid];
  if (tid<64){
    const int v=vbase+tid;
    int w[8];
    #pragma unroll
    for (int i=0;i<8;++i) w[i]=walks[v*8+i];
    int u[8];
    #pragma unroll
    for (int i=0;i<8;++i){
      int ui=i;
      #pragma unroll
      for (int j=7;j>=0;--j) if (j<=i && w[j]==w[i]) ui=j;  // first occurrence
      u[i]=ui;
    }
    #pragma unroll
    for (int t=0;t<8;++t) m_u[tid][t]=u[7-t];
    if (dirb==0){
      const float dmx=(float)(*dmaxp);
      #pragma unroll
      for (int t=0;t<8;++t){
        int nd=w[7-t];
        M_node[(size_t)v*8+t]=nd;
        M_dd[(size_t)v*8+t]=(float)degs[nd]/dmx;
      }
    }
  }
  float hst[8];
  #pragma unroll
  for (int w=0;w<8;++w) hst[w]=0.f;
  __syncthreads();

  const float4* WR4=(const float4*)wrec;
  const int ycol = dirb ? 64 : 0;
  #define HROW(w) (&hbuf[wkb+(w)][0])
  for (int q=0;q<8;++q){
    const int p = dirb ? 7-q : q;
    float a0[8],a1[8],a2[8];
    #pragma unroll
    for (int w=0;w<8;++w){ a0[w]=sb_bhh[lane]; a1[w]=sb_bhh[64+lane]; a2[w]=sb_bhh[128+lane]; }
    if (q) MM3_8(WR4,HROW,a0,a1,a2);       // q==0: h==0
    #pragma unroll
    for (int w=0;w<8;++w){
      const int u=m_u[wkb+w][p];
      const float xr=tbl[u*192+lane], xz=tbl[u*192+64+lane], xn=tbl[u*192+128+lane];
      const float r=sigm(xr+a0[w]);
      const float z=sigm(xz+a1[w]);
      const float n=tanh_(xn+r*a2[w]);
      hst[w]=(1.f-z)*n+z*hst[w];
    }
    __syncthreads();                        // all MM3 reads of h_q done
    #pragma unroll
    for (int w=0;w<8;++w){
      hbuf[wkb+w][lane]=hst[w];
      XGE[((size_t)(vbase+wkb+w)*8+p)*192 + ycol + lane]=hst[w];
    }
    __syncthreads();                        // h_{q+1} visible
  }
  #undef HROW
  #pragma unroll
  for (int w=0;w<8;++w){
    const size_t o=(size_t)(vbase+wkb+w)*64+lane;
    if (dirb==0) HW[o] = 0.5f*hst[w];
    else         HW[o] += 0.5f*hst[w];
  }
}

// in-place projection: XGE row <- A^T yf + B^T yb + H2[node] + dd*wdeg + bihm
__global__ __launch_bounds__(512,1) void k_proj(
    const float* __restrict__ WLA, const float* __restrict__ WLB,
    const float* __restrict__ H2, const float* __restrict__ wdeg,
    const float* __restrict__ bihm,
    const int* __restrict__ M_node, const float* __restrict__ M_dd,
    float* __restrict__ XGE, const int rounds)
{
  __shared__ __align__(16) float wA[12288];
  __shared__ __align__(16) float wB[12288];
  __shared__ __align__(16) float yt[64][132];
  __shared__ float sb_wdeg[192], sb_bihm[192];
  __shared__ int   nd_l[64];
  __shared__ float dd_l[64];

  const int tid=threadIdx.x, wave=tid>>6, lane=tid&63;
  const int wkb=wave<<3;
  for (int i=tid;i<3072;i+=512){
    ((float4*)wA)[i]=((const float4*)WLA)[i];
    ((float4*)wB)[i]=((const float4*)WLB)[i];
  }
  if (tid<192){ sb_wdeg[tid]=wdeg[tid]; sb_bihm[tid]=bihm[tid]; }
  const float4* A4=(const float4*)wA;
  const float4* B4=(const float4*)wB;

  for (int rr=0;rr<rounds;++rr){
    const size_t r0 = ((size_t)blockIdx.x*rounds + rr)*64;
    __syncthreads();                        // prior round's yt reads done / weights staged
    for (int i=tid;i<2048;i+=512){
      int row=i>>5, c4=i&31;
      *(float4*)&yt[row][c4*4] = *(const float4*)&XGE[(r0+row)*192 + c4*4];
    }
    if (tid<64){ nd_l[tid]=M_node[r0+tid]; dd_l[tid]=M_dd[r0+tid]; }
    __syncthreads();
    float p0[8],p1[8],p2[8];
    #pragma unroll
    for (int w=0;w<8;++w){ p0[w]=0.f;p1[w]=0.f;p2[w]=0.f; }
    #define YF(w) (&yt[wkb+(w)][0])
    #define YB(w) (&yt[wkb+(w)][64])
    MM3_8(A4,YF,p0,p1,p2);
    MM3_8(B4,YB,p0,p1,p2);
    #undef YF
    #undef YB
    #pragma unroll
    for (int w=0;w<8;++w){
      const size_t row=r0+wkb+w;
      const int nd=nd_l[wkb+w];
      const float dd=dd_l[wkb+w];
      const size_t h2b=(size_t)nd*192;
      XGE[row*192+lane]     = p0[w] + H2[h2b+lane]     + dd*sb_wdeg[lane]     + sb_bihm[lane];
      XGE[row*192+64+lane]  = p1[w] + H2[h2b+64+lane]  + dd*sb_wdeg[64+lane]  + sb_bihm[64+lane];
      XGE[row*192+128+lane] = p2[w] + H2[h2b+128+lane] + dd*sb_wdeg[128+lane] + sb_bihm[128+lane];
    }
  }
}

__global__ __launch_bounds__(512,2) void k_main(
    const int* __restrict__ eids, const float* __restrict__ bhh_m,
    const float* __restrict__ WLm, const float* __restrict__ XGE,
    const float* __restrict__ E2, const float* __restrict__ HW,
    float* __restrict__ out)
{
  __shared__ __align__(16) float wrec[12288];
  __shared__ __align__(16) float hbuf[64][64];
  __shared__ float sb_bhh[192];
  const int tid=threadIdx.x, wave=tid>>6, lane=tid&63;
  const int wkb=wave<<3;
  const int vbase=blockIdx.x*64;
  for (int i=tid;i<3072;i+=512) ((float4*)wrec)[i]=((const float4*)WLm)[i];
  if (tid<192) sb_bhh[tid]=bhh_m[tid];
  float hst[8];
  #pragma unroll
  for (int w=0;w<8;++w){
    hst[w]=HW[(size_t)(vbase+wkb+w)*64+lane];
    hbuf[wkb+w][lane]=hst[w];
  }
  __syncthreads();
  const float4* WR4=(const float4*)wrec;
  #define HROW(w) (&hbuf[wkb+(w)][0])
  for (int t=0;t<15;++t){
    float a0[8],a1[8],a2[8];
    #pragma unroll
    for (int w=0;w<8;++w){ a0[w]=sb_bhh[lane]; a1[w]=sb_bhh[64+lane]; a2[w]=sb_bhh[128+lane]; }
    MM3_8(WR4,HROW,a0,a1,a2);
    #pragma unroll
    for (int w=0;w<8;++w){
      const int v=vbase+wkb+w;
      const float* xg;
      if (t&1) xg = E2 + (size_t)eids[v*7+(t>>1)]*192;
      else     xg = XGE + ((size_t)v*8+(t>>1))*192;
      const float r=sigm(xg[lane]      + a0[w]);
      const float z=sigm(xg[64+lane]   + a1[w]);
      const float n=tanh_(xg[128+lane] + r*a2[w]);
      hst[w]=(1.f-z)*n+z*hst[w];
    }
    __syncthreads();
    #pragma unroll
    for (int w=0;w<8;++w) hbuf[wkb+w][lane]=hst[w];
    __syncthreads();
  }
  #undef HROW
  #pragma unroll
  for (int w=0;w<8;++w) out[(size_t)(vbase+wkb+w)*64+lane]=hst[w];
}

extern "C" void kernel_launch(void* const* d_in, const int* in_sizes, int n_in,
                              void* d_out, int out_size, void* d_ws, size_t ws_size,
                              hipStream_t stream)
{
  const float* h      = (const float*)d_in[0];
  const float* e      = (const float*)d_in[2];
  const int*   walks  = (const int*)d_in[3];
  const int*   eids   = (const int*)d_in[4];
  const int*   degs   = (const int*)d_in[5];
  const float* wih_wf = (const float*)d_in[6];
  const float* whh_wf = (const float*)d_in[7];
  const float* bih_wf = (const float*)d_in[8];
  const float* bhh_wf = (const float*)d_in[9];
  const float* wih_wb = (const float*)d_in[10];
  const float* whh_wb = (const float*)d_in[11];
  const float* bih_wb = (const float*)d_in[12];
  const float* bhh_wb = (const float*)d_in[13];
  const float* wih_m  = (const float*)d_in[14];
  const float* whh_m  = (const float*)d_in[15];
  const float* bih_m  = (const float*)d_in[16];
  const float* bhh_m  = (const float*)d_in[17];
  const float* w_edge = (const float*)d_in[18];
  float* out = (float*)d_out;
  float* wsf = (float*)d_ws;

  float* WL   = wsf + OFF_WL;
  float* Tf   = wsf + OFF_TF;
  float* Tb   = wsf + OFF_TB;
  float* Me   = wsf + OFF_ME;
  float* WmhT = wsf + OFF_WMHT;
  float* wdeg = wsf + OFF_WDEG;
  int*   dmax = (int*)(wsf + OFF_DMAX);
  float* E2   = wsf + OFF_E2;
  float* H2   = wsf + OFF_H2;
  float* XGE  = wsf + OFF_XGE;
  float* HW   = wsf + OFF_HW;
  int*   MND  = (int*)(wsf + OFF_MND);
  float* MDD  = wsf + OFF_MDD;

  hipLaunchKernelGGL(k_init,      dim3(1),    dim3(64), 0, stream, dmax);
  hipLaunchKernelGGL(k_prep_wl,   dim3(240),  dim3(256),0, stream, whh_wf,whh_wb,whh_m,wih_m,WL);
  hipLaunchKernelGGL(k_prep_tbl,  dim3(12),   dim3(256),0, stream, wih_wf,bih_wf,wih_wb,bih_wb,Tf,Tb);
  hipLaunchKernelGGL(k_prep_misc, dim3(61),   dim3(256),0, stream, wih_m,w_edge,Me,WmhT,wdeg);
  hipLaunchKernelGGL(k_degmax,    dim3(1000), dim3(256),0, stream, walks,degs,dmax);
  hipLaunchKernelGGL(k_e2,        dim3(NEDGE),dim3(192),0, stream, e,Me,bih_m,E2);
  hipLaunchKernelGGL(k_h2,        dim3(NNODE),dim3(192),0, stream, h,WmhT,H2);
  // forward / backward walk GRUs (rec-only; y into XGE cols 0:64 / 64:128)
  hipLaunchKernelGGL(k_wgru,      dim3(500),  dim3(512),0, stream,
                     walks,degs,dmax, WL+0*12288, Tf, bhh_wf, XGE,HW,MND,MDD, 0);
  hipLaunchKernelGGL(k_wgru,      dim3(500),  dim3(512),0, stream,
                     walks,degs,dmax, WL+1*12288, Tb, bhh_wb, XGE,HW,MND,MDD, 1);
  // in-place projection (A,B) + H2/deg/bias epilogue
  hipLaunchKernelGGL(k_proj,      dim3(2000), dim3(512),0, stream,
                     WL+3*12288, WL+4*12288, H2, wdeg, bih_m, MND, MDD, XGE, 2);
  hipLaunchKernelGGL(k_main,      dim3(500),  dim3(512),0, stream,
                     eids,bhh_m, WL+2*12288, XGE,E2,HW, out);
  (void)in_sizes;(void)n_in;(void)out_size;(void)ws_size;
}

// Round 9
// 914.722 us; speedup vs baseline: 6.5825x; 1.0763x over previous
//
#include <hip/hip_runtime.h>
#include <math.h>

#define NWALK 32000
#define NNODE 8000
#define NEDGE 64000

// workspace layout (float offsets)
static const size_t OFF_WL   = 0;                          // 5 chunked 192x64 mats: wf,wb,m,A,B
static const size_t OFF_TF   = OFF_WL + 5*12288;           // T_f[8][192]
static const size_t OFF_TB   = OFF_TF + 1536;              // T_b[8][192]
static const size_t OFF_ME   = OFF_TB + 1536;              // M_edge[192][16]
static const size_t OFF_WMHT = OFF_ME + 3072;              // WmhT[64][192]
static const size_t OFF_WDEG = OFF_WMHT + 12288;           // wdeg[192]
static const size_t OFF_DMAX = OFF_WDEG + 192;             // int degmax (+pad)
static const size_t OFF_E2   = OFF_DMAX + 64;              // E2[64000][192]
static const size_t OFF_H2   = OFF_E2 + (size_t)NEDGE*192; // H2[8000][192]
static const size_t OFF_XGE  = OFF_H2 + (size_t)NNODE*192; // XGE[256000][192]
static const size_t OFF_HW   = OFF_XGE + (size_t)NWALK*8*192; // HW[32000][64]
static const size_t OFF_MND  = OFF_HW + (size_t)NWALK*64;  // M_node[256000] (int)
static const size_t OFF_MDD  = OFF_MND + (size_t)NWALK*8;  // M_dd[256000]

__device__ __forceinline__ float sigm(float x){ return 1.f/(1.f+__expf(-x)); }
__device__ __forceinline__ float tanh_(float x){ float e=__expf(2.f*x); return 1.f-2.f/(e+1.f); }

__global__ void k_init(int* dmax){ if (threadIdx.x==0) *dmax = 0; }

// chunked layout for MM3: dst[(k>>2)*768 + g*4 + (k&3)]
__global__ void k_prep_wl(const float* __restrict__ whh_wf, const float* __restrict__ whh_wb,
                          const float* __restrict__ whh_m,  const float* __restrict__ wih_m,
                          float* __restrict__ WL){
  int idx = blockIdx.x*256 + threadIdx.x;
  if (idx >= 5*12288) return;
  int m = idx / 12288, r = idx % 12288;
  int g = r >> 6, k = r & 63;
  float v;
  if      (m==0) v = whh_wf[g*64+k];
  else if (m==1) v = whh_wb[g*64+k];
  else if (m==2) v = whh_m [g*64+k];
  else if (m==3) v = wih_m [g*193 + 64  + k];   // A
  else           v = wih_m [g*193 + 128 + k];   // B
  WL[m*12288 + (k>>2)*768 + g*4 + (k&3)] = v;
}

__global__ void k_prep_tbl(const float* __restrict__ wih_wf, const float* __restrict__ bih_wf,
                           const float* __restrict__ wih_wb, const float* __restrict__ bih_wb,
                           float* __restrict__ Tf, float* __restrict__ Tb){
  int idx = blockIdx.x*256+threadIdx.x;
  if (idx >= 3072) return;
  int which = idx / 1536, r = idx % 1536;
  int u = r / 192, g = r % 192;
  float ang = (float)u * 0.78539816339744831f; // pi/4
  float s = sinf(ang), c = cosf(ang);
  if (which==0) Tf[u*192+g] = bih_wf[g] + wih_wf[g*2+0]*s + wih_wf[g*2+1]*c;
  else          Tb[u*192+g] = bih_wb[g] + wih_wb[g*2+0]*s + wih_wb[g*2+1]*c;
}

__global__ void k_prep_misc(const float* __restrict__ wih_m, const float* __restrict__ w_edge,
                            float* __restrict__ M, float* __restrict__ WmhT,
                            float* __restrict__ wdeg){
  int idx = blockIdx.x*256+threadIdx.x;
  if (idx < 3072){
    int g = idx >> 4, f = idx & 15;
    float acc = 0.f;
    for (int d=0; d<193; ++d) acc += wih_m[g*193+d]*w_edge[d*16+f];
    M[g*16+f] = acc;
  }
  int j = idx - 3072;
  if (j >= 0 && j < 12288){
    int k = j / 192, g = j % 192;
    WmhT[k*192+g] = wih_m[g*193+k];
  }
  int q = idx - 3072 - 12288;
  if (q >= 0 && q < 192) wdeg[q] = wih_m[q*193+192];
}

// degmax reduce + zero HW (needed for atomicAdd accumulation)
__global__ void k_degmax(const int* __restrict__ walks, const int* __restrict__ degs,
                         int* __restrict__ dmax, float* __restrict__ HW){
  int idx = blockIdx.x*256+threadIdx.x;
  int v = 0;
  if (idx < NWALK*8) v = degs[walks[idx]];
  #pragma unroll
  for (int off=32; off; off>>=1) v = max(v, __shfl_xor(v, off));
  if ((threadIdx.x & 63)==0) atomicMax(dmax, v);
  for (size_t i=idx; i<(size_t)NWALK*64; i+=256000) HW[i]=0.f;
}

// fused: blocks [0,NEDGE) -> E2 rows; blocks [NEDGE, NEDGE+NNODE) -> H2 rows
__global__ void k_e2h2(const float* __restrict__ e, const float* __restrict__ M,
                       const float* __restrict__ bih_m,
                       const float* __restrict__ h, const float* __restrict__ WmhT,
                       float* __restrict__ E2, float* __restrict__ H2){
  const int bx = blockIdx.x;
  const int g = threadIdx.x;
  if (bx < NEDGE){
    __shared__ float ev[16];
    if (g < 16) ev[g] = e[bx*16+g];
    __syncthreads();
    float acc = bih_m[g];
    #pragma unroll
    for (int f=0; f<16; ++f) acc += ev[f]*M[g*16+f];
    E2[(size_t)bx*192+g] = acc;
  } else {
    const int node = bx - NEDGE;
    __shared__ float hv[64];
    if (g < 64) hv[g] = h[node*64+g];
    __syncthreads();
    float acc = 0.f;
    for (int k=0;k<64;++k) acc += hv[k]*WmhT[k*192+g];
    H2[(size_t)node*192+g] = acc;
  }
}

#define DOT4(a,b) ((a).x*(b).x+(a).y*(b).y+(a).z*(b).z+(a).w*(b).w)
// 3-gate matvec, 8 walks/wave. unroll 2: cap live weight-load registers.
#define MM3_8(W4, HPTR, A0, A1, A2) do { \
  _Pragma("unroll 2") \
  for (int c=0;c<16;++c){ \
    float4 w0=(W4)[c*192+lane]; \
    float4 w1=(W4)[c*192+64+lane]; \
    float4 w2=(W4)[c*192+128+lane]; \
    _Pragma("unroll") \
    for (int w=0;w<8;++w){ \
      float4 hv=*(const float4*)(HPTR(w)+c*4); \
      A0[w]+=DOT4(w0,hv); A1[w]+=DOT4(w1,hv); A2[w]+=DOT4(w2,hv); } } \
} while(0)

// fused fwd+bwd recurrent walk GRU (8 walks/wave, 64 walks/block)
// blocks [0,500): forward; [500,1000): backward. y -> XGE col 0:64 / 64:128
__global__ __launch_bounds__(512,2) void k_wgru(
    const int* __restrict__ walks, const int* __restrict__ degs,
    const int* __restrict__ dmaxp,
    const float* __restrict__ WL0,   // chunked rec weights (f at +0, b at +12288)
    const float* __restrict__ Tf, const float* __restrict__ Tb,
    const float* __restrict__ bhh_f, const float* __restrict__ bhh_b,
    float* __restrict__ XGE, float* __restrict__ HW,
    int* __restrict__ M_node, float* __restrict__ M_dd)
{
  __shared__ __align__(16) float wrec[12288];
  __shared__ __align__(16) float hbuf[64][64];
  __shared__ __align__(16) float tbl[1536];
  __shared__ float sb_bhh[192];
  __shared__ int   m_u[64][8];

  const int bx = blockIdx.x;
  const int dirb = (bx >= 500);
  const int tid = threadIdx.x;
  const int wave = tid>>6, lane = tid&63;
  const int wkb = wave<<3;
  const int vbase = (dirb ? bx-500 : bx)*64;

  const float* WLb = WL0 + (dirb ? 12288 : 0);
  const float* TBL = dirb ? Tb : Tf;
  const float* bhh = dirb ? bhh_b : bhh_f;

  for (int i=tid;i<3072;i+=512) ((float4*)wrec)[i]=((const float4*)WLb)[i];
  for (int i=tid;i<1536;i+=512) tbl[i]=TBL[i];
  if (tid<192) sb_bhh[tid]=bhh[tid];
  if (tid<64){
    const int v=vbase+tid;
    int w[8];
    #pragma unroll
    for (int i=0;i<8;++i) w[i]=walks[v*8+i];
    int u[8];
    #pragma unroll
    for (int i=0;i<8;++i){
      int ui=i;
      #pragma unroll
      for (int j=7;j>=0;--j) if (j<=i && w[j]==w[i]) ui=j;  // first occurrence
      u[i]=ui;
    }
    #pragma unroll
    for (int t=0;t<8;++t) m_u[tid][t]=u[7-t];
    if (!dirb){
      const float dmx=(float)(*dmaxp);
      #pragma unroll
      for (int t=0;t<8;++t){
        int nd=w[7-t];
        M_node[(size_t)v*8+t]=nd;
        M_dd[(size_t)v*8+t]=(float)degs[nd]/dmx;
      }
    }
  }
  float hst[8];
  #pragma unroll
  for (int w=0;w<8;++w) hst[w]=0.f;
  __syncthreads();

  const float4* WR4=(const float4*)wrec;
  const int ycol = dirb ? 64 : 0;
  #define HROW(w) (&hbuf[wkb+(w)][0])
  for (int q=0;q<8;++q){
    const int p = dirb ? 7-q : q;
    float a0[8],a1[8],a2[8];
    #pragma unroll
    for (int w=0;w<8;++w){ a0[w]=sb_bhh[lane]; a1[w]=sb_bhh[64+lane]; a2[w]=sb_bhh[128+lane]; }
    if (q) MM3_8(WR4,HROW,a0,a1,a2);       // q==0: h==0
    #pragma unroll
    for (int w=0;w<8;++w){
      const int u=m_u[wkb+w][p];
      const float xr=tbl[u*192+lane], xz=tbl[u*192+64+lane], xn=tbl[u*192+128+lane];
      const float r=sigm(xr+a0[w]);
      const float z=sigm(xz+a1[w]);
      const float n=tanh_(xn+r*a2[w]);
      hst[w]=(1.f-z)*n+z*hst[w];
    }
    __syncthreads();                        // all MM3 reads of h_q done
    #pragma unroll
    for (int w=0;w<8;++w){
      hbuf[wkb+w][lane]=hst[w];
      XGE[((size_t)(vbase+wkb+w)*8+p)*192 + ycol + lane]=hst[w];
    }
    __syncthreads();                        // h_{q+1} visible
  }
  #undef HROW
  #pragma unroll
  for (int w=0;w<8;++w)
    atomicAdd(&HW[(size_t)(vbase+wkb+w)*64+lane], 0.5f*hst[w]);
}

// in-place projection: XGE row <- A^T yf + B^T yb + H2[node] + dd*wdeg + bihm
// weights read directly from global (L2-resident, coalesced) -> small LDS
__global__ __launch_bounds__(512,2) void k_proj(
    const float* __restrict__ WLA, const float* __restrict__ WLB,
    const float* __restrict__ H2, const float* __restrict__ wdeg,
    const float* __restrict__ bihm,
    const int* __restrict__ M_node, const float* __restrict__ M_dd,
    float* __restrict__ XGE)
{
  __shared__ __align__(16) float yt[64][132];
  __shared__ float sb_wdeg[192], sb_bihm[192];
  __shared__ int   nd_l[64];
  __shared__ float dd_l[64];

  const int tid=threadIdx.x, wave=tid>>6, lane=tid&63;
  const int wkb=wave<<3;
  const size_t r0 = (size_t)blockIdx.x*64;

  if (tid<192){ sb_wdeg[tid]=wdeg[tid]; sb_bihm[tid]=bihm[tid]; }
  for (int i=tid;i<2048;i+=512){
    int row=i>>5, c4=i&31;
    *(float4*)&yt[row][c4*4] = *(const float4*)&XGE[(r0+row)*192 + c4*4];
  }
  if (tid<64){ nd_l[tid]=M_node[r0+tid]; dd_l[tid]=M_dd[r0+tid]; }
  __syncthreads();

  const float4* A4=(const float4*)WLA;
  const float4* B4=(const float4*)WLB;
  float p0[8],p1[8],p2[8];
  #pragma unroll
  for (int w=0;w<8;++w){ p0[w]=0.f;p1[w]=0.f;p2[w]=0.f; }
  #pragma unroll 2
  for (int c=0;c<16;++c){
    float4 wa0=A4[c*192+lane], wa1=A4[c*192+64+lane], wa2=A4[c*192+128+lane];
    float4 wb0=B4[c*192+lane], wb1=B4[c*192+64+lane], wb2=B4[c*192+128+lane];
    #pragma unroll
    for (int w=0;w<8;++w){
      float4 yf=*(const float4*)&yt[wkb+w][c*4];
      float4 yb=*(const float4*)&yt[wkb+w][64+c*4];
      p0[w]+=DOT4(wa0,yf)+DOT4(wb0,yb);
      p1[w]+=DOT4(wa1,yf)+DOT4(wb1,yb);
      p2[w]+=DOT4(wa2,yf)+DOT4(wb2,yb);
    }
  }
  #pragma unroll
  for (int w=0;w<8;++w){
    const size_t row=r0+wkb+w;
    const int nd=nd_l[wkb+w];
    const float dd=dd_l[wkb+w];
    const size_t h2b=(size_t)nd*192;
    XGE[row*192+lane]     = p0[w] + H2[h2b+lane]     + dd*sb_wdeg[lane]     + sb_bihm[lane];
    XGE[row*192+64+lane]  = p1[w] + H2[h2b+64+lane]  + dd*sb_wdeg[64+lane]  + sb_bihm[64+lane];
    XGE[row*192+128+lane] = p2[w] + H2[h2b+128+lane] + dd*sb_wdeg[128+lane] + sb_bihm[128+lane];
  }
}

__global__ __launch_bounds__(512,2) void k_main(
    const int* __restrict__ eids, const float* __restrict__ bhh_m,
    const float* __restrict__ WLm, const float* __restrict__ XGE,
    const float* __restrict__ E2, const float* __restrict__ HW,
    float* __restrict__ out)
{
  __shared__ __align__(16) float wrec[12288];
  __shared__ __align__(16) float hbuf[64][64];
  __shared__ float sb_bhh[192];
  const int tid=threadIdx.x, wave=tid>>6, lane=tid&63;
  const int wkb=wave<<3;
  const int vbase=blockIdx.x*64;
  for (int i=tid;i<3072;i+=512) ((float4*)wrec)[i]=((const float4*)WLm)[i];
  if (tid<192) sb_bhh[tid]=bhh_m[tid];
  float hst[8];
  #pragma unroll
  for (int w=0;w<8;++w){
    hst[w]=HW[(size_t)(vbase+wkb+w)*64+lane];
    hbuf[wkb+w][lane]=hst[w];
  }
  __syncthreads();
  const float4* WR4=(const float4*)wrec;
  #define HROW(w) (&hbuf[wkb+(w)][0])
  for (int t=0;t<15;++t){
    float a0[8],a1[8],a2[8];
    #pragma unroll
    for (int w=0;w<8;++w){ a0[w]=sb_bhh[lane]; a1[w]=sb_bhh[64+lane]; a2[w]=sb_bhh[128+lane]; }
    MM3_8(WR4,HROW,a0,a1,a2);
    #pragma unroll
    for (int w=0;w<8;++w){
      const int v=vbase+wkb+w;
      const float* xg;
      if (t&1) xg = E2 + (size_t)eids[v*7+(t>>1)]*192;
      else     xg = XGE + ((size_t)v*8+(t>>1))*192;
      const float r=sigm(xg[lane]      + a0[w]);
      const float z=sigm(xg[64+lane]   + a1[w]);
      const float n=tanh_(xg[128+lane] + r*a2[w]);
      hst[w]=(1.f-z)*n+z*hst[w];
    }
    __syncthreads();
    #pragma unroll
    for (int w=0;w<8;++w) hbuf[wkb+w][lane]=hst[w];
    __syncthreads();
  }
  #undef HROW
  #pragma unroll
  for (int w=0;w<8;++w) out[(size_t)(vbase+wkb+w)*64+lane]=hst[w];
}

extern "C" void kernel_launch(void* const* d_in, const int* in_sizes, int n_in,
                              void* d_out, int out_size, void* d_ws, size_t ws_size,
                              hipStream_t stream)
{
  const float* h      = (const float*)d_in[0];
  const float* e      = (const float*)d_in[2];
  const int*   walks  = (const int*)d_in[3];
  const int*   eids   = (const int*)d_in[4];
  const int*   degs   = (const int*)d_in[5];
  const float* wih_wf = (const float*)d_in[6];
  const float* whh_wf = (const float*)d_in[7];
  const float* bih_wf = (const float*)d_in[8];
  const float* bhh_wf = (const float*)d_in[9];
  const float* wih_wb = (const float*)d_in[10];
  const float* whh_wb = (const float*)d_in[11];
  const float* bih_wb = (const float*)d_in[12];
  const float* bhh_wb = (const float*)d_in[13];
  const float* wih_m  = (const float*)d_in[14];
  const float* whh_m  = (const float*)d_in[15];
  const float* bih_m  = (const float*)d_in[16];
  const float* bhh_m  = (const float*)d_in[17];
  const float* w_edge = (const float*)d_in[18];
  float* out = (float*)d_out;
  float* wsf = (float*)d_ws;

  float* WL   = wsf + OFF_WL;
  float* Tf   = wsf + OFF_TF;
  float* Tb   = wsf + OFF_TB;
  float* Me   = wsf + OFF_ME;
  float* WmhT = wsf + OFF_WMHT;
  float* wdeg = wsf + OFF_WDEG;
  int*   dmax = (int*)(wsf + OFF_DMAX);
  float* E2   = wsf + OFF_E2;
  float* H2   = wsf + OFF_H2;
  float* XGE  = wsf + OFF_XGE;
  float* HW   = wsf + OFF_HW;
  int*   MND  = (int*)(wsf + OFF_MND);
  float* MDD  = wsf + OFF_MDD;

  hipLaunchKernelGGL(k_init,      dim3(1),    dim3(64), 0, stream, dmax);
  hipLaunchKernelGGL(k_prep_wl,   dim3(240),  dim3(256),0, stream, whh_wf,whh_wb,whh_m,wih_m,WL);
  hipLaunchKernelGGL(k_prep_tbl,  dim3(12),   dim3(256),0, stream, wih_wf,bih_wf,wih_wb,bih_wb,Tf,Tb);
  hipLaunchKernelGGL(k_prep_misc, dim3(61),   dim3(256),0, stream, wih_m,w_edge,Me,WmhT,wdeg);
  hipLaunchKernelGGL(k_degmax,    dim3(1000), dim3(256),0, stream, walks,degs,dmax,HW);
  hipLaunchKernelGGL(k_e2h2,      dim3(NEDGE+NNODE),dim3(192),0, stream, e,Me,bih_m,h,WmhT,E2,H2);
  // fused forward+backward walk GRUs (rec-only; y into XGE cols 0:64 / 64:128)
  hipLaunchKernelGGL(k_wgru,      dim3(1000), dim3(512),0, stream,
                     walks,degs,dmax, WL, Tf,Tb, bhh_wf,bhh_wb, XGE,HW,MND,MDD);
  // in-place projection (A,B from global/L2) + H2/deg/bias epilogue
  hipLaunchKernelGGL(k_proj,      dim3(4000), dim3(512),0, stream,
                     WL+3*12288, WL+4*12288, H2, wdeg, bih_m, MND, MDD, XGE);
  hipLaunchKernelGGL(k_main,      dim3(500),  dim3(512),0, stream,
                     eids,bhh_m, WL+2*12288, XGE,E2,HW, out);
  (void)in_sizes;(void)n_in;(void)out_size;(void)ws_size;
}

// Round 12
// 571.034 us; speedup vs baseline: 10.5443x; 1.6019x over previous
//
#include <hip/hip_runtime.h>
#include <math.h>

#define NWALK 32000
#define NNODE 8000
#define NEDGE 64000

typedef __attribute__((ext_vector_type(8))) short short8v;   // 8 bf16 (4 VGPRs)
typedef __attribute__((ext_vector_type(4))) float f32x4;     // MFMA C/D

// workspace layout (float offsets)
static const size_t OFF_WL   = 0;                          // slots 3,4 used (A,B chunked for k_proj)
static const size_t OFF_ME   = OFF_WL + 5*12288;           // M_edge[192][16]
static const size_t OFF_WMHT = OFF_ME + 3072;              // WmhT[64][192]
static const size_t OFF_WDEG = OFF_WMHT + 12288;           // wdeg[192]
static const size_t OFF_DMAX = OFF_WDEG + 192;             // int degmax (+pad)
static const size_t OFF_E2   = OFF_DMAX + 64;              // E2[64000][192]
static const size_t OFF_H2   = OFF_E2 + (size_t)NEDGE*192; // H2[8000][192]
static const size_t OFF_XGE  = OFF_H2 + (size_t)NNODE*192; // XGE[256000][192]
static const size_t OFF_HW   = OFF_XGE + (size_t)NWALK*8*192; // HW[32000][64]
static const size_t OFF_MND  = OFF_HW + (size_t)NWALK*64;  // M_node[256000] (int)
static const size_t OFF_MDD  = OFF_MND + (size_t)NWALK*8;  // M_dd[256000]
static const size_t OFF_TFP  = OFF_MDD + (size_t)NWALK*8;  // Tf'[8][196] (bih all; bhh folded r,z only)
static const size_t OFF_TBP  = OFF_TFP + 1568;             // Tb'[8][196]
static const size_t OFF_WB   = OFF_TBP + 1568;             // bf16 hi/lo A-frags: 3 mats x 2 hh x 12288 ushort

__device__ __forceinline__ float sigm(float x){ return 1.f/(1.f+__expf(-x)); }
__device__ __forceinline__ float tanh_(float x){ float e=__expf(2.f*x); return 1.f-2.f/(e+1.f); }
__device__ __forceinline__ unsigned short f2bf(float x){
  unsigned u = __float_as_uint(x);
  unsigned r = (u + 0x7FFFu + ((u>>16)&1u)) >> 16;   // RNE
  return (unsigned short)r;
}
__device__ __forceinline__ float bf2f(unsigned short h){
  return __uint_as_float(((unsigned)h)<<16);
}

__global__ void k_init(int* dmax){ if (threadIdx.x==0) *dmax = 0; }

// chunked f32 layout for k_proj MM3: only A,B (m=3,4)
__global__ void k_prep_wl(const float* __restrict__ wih_m, float* __restrict__ WL){
  int idx = blockIdx.x*256 + threadIdx.x;
  if (idx >= 2*12288) return;
  int m = 3 + idx/12288, r = idx % 12288;
  int g = r >> 6, k = r & 63;
  float v = wih_m[g*193 + (m==3?64:128) + k];
  WL[(size_t)m*12288 + (k>>2)*768 + g*4 + (k&3)] = v;
}

// bf16 hi/lo MFMA A-fragments for whh_wf / whh_wb / whh_m, split by hidden-half hh.
// local tile a=g'*2+b -> global tile t=4g'+2hh+b; frag f=a*4+c*2+p (c=k-chunk, p=0 hi/1 lo)
// ushort addr = (mat*2+hh)*12288 + f*512 + lane*8 + i
// A[row=16t+(lane&15)][k=32c+8*(lane>>4)+i]
__global__ void k_prep_wb(const float* __restrict__ whh_wf, const float* __restrict__ whh_wb,
                          const float* __restrict__ whh_m, unsigned short* __restrict__ WB){
  int idx = blockIdx.x*256+threadIdx.x;
  if (idx >= 3*2*12288) return;
  int mat = idx/24576; int r1 = idx%24576;
  int hh  = r1/12288;  int r2 = r1%12288;
  int f   = r2/512;    int r3 = r2%512;
  int lane= r3>>3, i = r3&7;
  int a = f>>2, c=(f>>1)&1, p=f&1;
  int t = 4*(a>>1) + 2*hh + (a&1);
  int row = 16*t + (lane&15);
  int k = 32*c + 8*(lane>>4) + i;
  const float* W = (mat==0)? whh_wf : ((mat==1)? whh_wb : whh_m);
  float val = W[row*64+k];
  unsigned short hi = f2bf(val);
  WB[idx] = (p==0) ? hi : f2bf(val - bf2f(hi));
}

// padded gate tables (stride 196): bih always; bhh folded ONLY for r,z rows (g<128).
// n-gate bhh (g in [128,192)) is multiplied by r in the GRU -> kept separate.
__global__ void k_prep_tblp(const float* __restrict__ wih_wf,const float* __restrict__ bih_wf,
                            const float* __restrict__ bhh_wf,
                            const float* __restrict__ wih_wb,const float* __restrict__ bih_wb,
                            const float* __restrict__ bhh_wb,
                            float* __restrict__ Tfp, float* __restrict__ Tbp){
  int idx = blockIdx.x*256+threadIdx.x;
  if (idx >= 2*1568) return;
  int which = idx/1568, r = idx%1568;
  int u = r/196, g = r%196;
  float val = 0.f;
  if (g < 192){
    float ang = (float)u * 0.78539816339744831f;
    float s = sinf(ang), cc = cosf(ang);
    if (!which) val = bih_wf[g] + wih_wf[g*2]*s + wih_wf[g*2+1]*cc + (g<128? bhh_wf[g] : 0.f);
    else        val = bih_wb[g] + wih_wb[g*2]*s + wih_wb[g*2+1]*cc + (g<128? bhh_wb[g] : 0.f);
  }
  (which? Tbp : Tfp)[u*196+g] = val;
}

__global__ void k_prep_misc(const float* __restrict__ wih_m, const float* __restrict__ w_edge,
                            float* __restrict__ M, float* __restrict__ WmhT,
                            float* __restrict__ wdeg){
  int idx = blockIdx.x*256+threadIdx.x;
  if (idx < 3072){
    int g = idx >> 4, f = idx & 15;
    float acc = 0.f;
    for (int d=0; d<193; ++d) acc += wih_m[g*193+d]*w_edge[d*16+f];
    M[g*16+f] = acc;
  }
  int j = idx - 3072;
  if (j >= 0 && j < 12288){
    int k = j / 192, g = j % 192;
    WmhT[k*192+g] = wih_m[g*193+k];
  }
  int q = idx - 3072 - 12288;
  if (q >= 0 && q < 192) wdeg[q] = wih_m[q*193+192];
}

// degmax reduce + zero HW (atomicAdd accumulation target)
__global__ void k_degmax(const int* __restrict__ walks, const int* __restrict__ degs,
                         int* __restrict__ dmax, float* __restrict__ HW){
  int idx = blockIdx.x*256+threadIdx.x;
  int v = 0;
  if (idx < NWALK*8) v = degs[walks[idx]];
  #pragma unroll
  for (int off=32; off; off>>=1) v = max(v, __shfl_xor(v, off));
  if ((threadIdx.x & 63)==0) atomicMax(dmax, v);
  for (size_t i=idx; i<(size_t)NWALK*64; i+=256000) HW[i]=0.f;
}

// fused: E2 rows (bih_m always; bhh_m folded only g<128) and H2 rows
__global__ void k_e2h2(const float* __restrict__ e, const float* __restrict__ M,
                       const float* __restrict__ bih_m, const float* __restrict__ bhh_m,
                       const float* __restrict__ h, const float* __restrict__ WmhT,
                       float* __restrict__ E2, float* __restrict__ H2){
  const int bx = blockIdx.x;
  const int g = threadIdx.x;
  if (bx < NEDGE){
    __shared__ float ev[16];
    if (g < 16) ev[g] = e[bx*16+g];
    __syncthreads();
    float acc = bih_m[g] + (g<128? bhh_m[g] : 0.f);
    #pragma unroll
    for (int f=0; f<16; ++f) acc += ev[f]*M[g*16+f];
    E2[(size_t)bx*192+g] = acc;
  } else {
    const int node = bx - NEDGE;
    __shared__ float hv[64];
    if (g < 64) hv[g] = h[node*64+g];
    __syncthreads();
    float acc = 0.f;
    for (int k=0;k<64;++k) acc += hv[k]*WmhT[k*192+g];
    H2[(size_t)node*192+g] = acc;
  }
}

// 6 MFMA hi/lo-split matvec chunk for one 16-row tile a:
// C = Whi*hhi + Whi*hlo + Wlo*hhi  (dropping lo*lo ~ 2^-18)
#define MM6(a, BH0, BH1, BL0, BL1, OUT) do { \
  f32x4 acc_={0.f,0.f,0.f,0.f}; \
  acc_=__builtin_amdgcn_mfma_f32_16x16x32_bf16(afr[(a)*4+0],BH0,acc_,0,0,0); \
  acc_=__builtin_amdgcn_mfma_f32_16x16x32_bf16(afr[(a)*4+2],BH1,acc_,0,0,0); \
  acc_=__builtin_amdgcn_mfma_f32_16x16x32_bf16(afr[(a)*4+0],BL0,acc_,0,0,0); \
  acc_=__builtin_amdgcn_mfma_f32_16x16x32_bf16(afr[(a)*4+2],BL1,acc_,0,0,0); \
  acc_=__builtin_amdgcn_mfma_f32_16x16x32_bf16(afr[(a)*4+1],BH0,acc_,0,0,0); \
  acc_=__builtin_amdgcn_mfma_f32_16x16x32_bf16(afr[(a)*4+3],BH1,acc_,0,0,0); \
  OUT=acc_; \
} while(0)

// pack 4 floats -> hi uint2 + lo uint2 (bf16 split)
__device__ __forceinline__ void pack_hilo(const float* hn, uint2* whi, uint2* wlo){
  unsigned short h0=f2bf(hn[0]), h1=f2bf(hn[1]), h2=f2bf(hn[2]), h3=f2bf(hn[3]);
  whi->x = (unsigned)h0 | ((unsigned)h1<<16);
  whi->y = (unsigned)h2 | ((unsigned)h3<<16);
  unsigned short l0=f2bf(hn[0]-bf2f(h0)), l1=f2bf(hn[1]-bf2f(h1));
  unsigned short l2=f2bf(hn[2]-bf2f(h2)), l3=f2bf(hn[3]-bf2f(h3));
  wlo->x = (unsigned)l0 | ((unsigned)l1<<16);
  wlo->y = (unsigned)l2 | ((unsigned)l3<<16);
}

// ---------------------------------------------------------------------------
// MFMA walk-GRU, hi/lo split. 256 thr = 2 groups x 2 waves; 16 walks/group.
// Wave hh handles hidden j in [32hh, 32hh+32). n-gate bhh kept in regs,
// applied INSIDE r*( ). blocks [0,1000): forward; [1000,2000): backward.
// ---------------------------------------------------------------------------
__global__ __launch_bounds__(256,1) void k_wgru_m(
    const int* __restrict__ walks, const int* __restrict__ degs,
    const int* __restrict__ dmaxp, const unsigned short* __restrict__ WB,
    const float* __restrict__ Tfp, const float* __restrict__ Tbp,
    const float* __restrict__ bhh_f, const float* __restrict__ bhh_b,
    float* __restrict__ XGE, float* __restrict__ HW,
    int* __restrict__ M_node, float* __restrict__ M_dd)
{
  __shared__ float tbl[1568];
  __shared__ int   m_u[32][8];
  __shared__ unsigned short hhi[2][2][16][64];   // [buf][grp][walk][j]
  __shared__ unsigned short hlo[2][2][16][64];
  const int bx=blockIdx.x;
  const int dirb = (bx>=1000);
  const int tid=threadIdx.x, wave=tid>>6, lane=tid&63;
  const int grp=wave>>1, hh=wave&1;
  const int wl=lane&15, ag=lane>>4;
  const int vbase=(dirb?bx-1000:bx)*32;
  const int v = vbase + grp*16 + wl;

  const float* TS = dirb? Tbp : Tfp;
  const float* BH = dirb? bhh_b : bhh_f;
  float bhhn[8];
  #pragma unroll
  for (int b=0;b<2;++b)
    #pragma unroll
    for (int r=0;r<4;++r)
      bhhn[4*b+r] = BH[128 + 32*hh + 16*b + 4*ag + r];   // n-gate hidden bias
  for (int i=tid;i<1568;i+=256) tbl[i]=TS[i];
  if (tid<32){
    const int vv=vbase+tid;
    int w[8];
    #pragma unroll
    for (int i=0;i<8;++i) w[i]=walks[vv*8+i];
    int u[8];
    #pragma unroll
    for (int i=0;i<8;++i){
      int ui=i;
      #pragma unroll
      for (int j=7;j>=0;--j) if (j<=i && w[j]==w[i]) ui=j;   // first occurrence
      u[i]=ui;
    }
    #pragma unroll
    for (int t=0;t<8;++t) m_u[tid][t]=u[7-t];
    if (!dirb){
      const float dmx=(float)(*dmaxp);
      #pragma unroll
      for (int t=0;t<8;++t){
        int nd=w[7-t];
        M_node[(size_t)vv*8+t]=nd;
        M_dd[(size_t)vv*8+t]=(float)degs[nd]/dmx;
      }
    }
  }
  short8v afr[24];
  const short8v* WBv = (const short8v*)(WB + (size_t)(dirb*2+hh)*12288);
  #pragma unroll
  for (int f=0;f<24;++f) afr[f]=WBv[f*64+lane];
  __syncthreads();

  float hold[8];
  #pragma unroll
  for (int i=0;i<8;++i) hold[i]=0.f;
  const int swz = (wl&7)<<4;
  const int ycol = dirb?64:0;
  const int o0 = (wl*128 + 16*ag) ^ swz;        // k-chunk 0 read offset
  const int o1 = (wl*128 + 64 + 16*ag) ^ swz;   // k-chunk 1

  for (int q=0;q<8;++q){
    const int p_ = dirb?7-q:q;
    const int cur = q&1;
    f32x4 C[6];
    if (q){
      const char* Hb=(const char*)&hhi[cur][grp][0][0];
      const char* Lb=(const char*)&hlo[cur][grp][0][0];
      short8v bh0=*(const short8v*)(Hb+o0), bh1=*(const short8v*)(Hb+o1);
      short8v bl0=*(const short8v*)(Lb+o0), bl1=*(const short8v*)(Lb+o1);
      MM6(0,bh0,bh1,bl0,bl1,C[0]); MM6(1,bh0,bh1,bl0,bl1,C[1]);
      MM6(2,bh0,bh1,bl0,bl1,C[2]); MM6(3,bh0,bh1,bl0,bl1,C[3]);
      MM6(4,bh0,bh1,bl0,bl1,C[4]); MM6(5,bh0,bh1,bl0,bl1,C[5]);
    } else {
      #pragma unroll
      for (int a=0;a<6;++a) C[a]=(f32x4){0.f,0.f,0.f,0.f};
    }
    const int u = m_u[grp*16+wl][p_];
    const float* tb = &tbl[u*196];
    float hnew[8];
    #pragma unroll
    for (int b=0;b<2;++b){
      const int j0 = 32*hh + 16*b + 4*ag;
      f32x4 xr = *(const f32x4*)(tb + j0);
      f32x4 xz = *(const f32x4*)(tb + 64 + j0);
      f32x4 xn = *(const f32x4*)(tb + 128 + j0);
      #pragma unroll
      for (int r=0;r<4;++r){
        float rr = sigm(xr[r] + C[b][r]);
        float zz = sigm(xz[r] + C[2+b][r]);
        float nn = tanh_(xn[r] + rr*(C[4+b][r] + bhhn[4*b+r]));   // bhh_n inside r*()
        hnew[4*b+r] = (1.f-zz)*nn + zz*hold[4*b+r];
      }
    }
    char* Hw=(char*)&hhi[cur^1][grp][0][0];
    char* Lw=(char*)&hlo[cur^1][grp][0][0];
    #pragma unroll
    for (int b=0;b<2;++b){
      const int j0 = 32*hh + 16*b + 4*ag;
      *(f32x4*)&XGE[((size_t)v*8+p_)*192 + ycol + j0] =
        (f32x4){hnew[4*b],hnew[4*b+1],hnew[4*b+2],hnew[4*b+3]};
      uint2 whi, wlo;
      pack_hilo(&hnew[4*b], &whi, &wlo);
      const int off = (wl*128 + j0*2) ^ swz;
      *(uint2*)(Hw+off)=whi;
      *(uint2*)(Lw+off)=wlo;
    }
    #pragma unroll
    for (int i=0;i<8;++i) hold[i]=hnew[i];
    __syncthreads();
  }
  #pragma unroll
  for (int b=0;b<2;++b)
    #pragma unroll
    for (int r=0;r<4;++r)
      atomicAdd(&HW[(size_t)v*64 + 32*hh+16*b+4*ag + r], 0.5f*hold[4*b+r]);
}

// MFMA main-GRU, hi/lo split, same 2-wave split; 15 steps; xg from XGE/E2.
// bhh_m n-gate rows kept in regs, applied inside r*( ).
__global__ __launch_bounds__(256,1) void k_main_m(
    const int* __restrict__ eids, const unsigned short* __restrict__ WB,
    const float* __restrict__ bhh_m,
    const float* __restrict__ XGE, const float* __restrict__ E2,
    const float* __restrict__ HW, float* __restrict__ out)
{
  __shared__ unsigned short hhi[2][2][16][64];
  __shared__ unsigned short hlo[2][2][16][64];
  const int tid=threadIdx.x, wave=tid>>6, lane=tid&63;
  const int grp=wave>>1, hh=wave&1;
  const int wl=lane&15, ag=lane>>4;
  const int v = blockIdx.x*32 + grp*16 + wl;
  float bhhn[8];
  #pragma unroll
  for (int b=0;b<2;++b)
    #pragma unroll
    for (int r=0;r<4;++r)
      bhhn[4*b+r] = bhh_m[128 + 32*hh + 16*b + 4*ag + r];
  short8v afr[24];
  const short8v* WBv = (const short8v*)(WB + (size_t)(2*2+hh)*12288);
  #pragma unroll
  for (int f=0;f<24;++f) afr[f]=WBv[f*64+lane];
  const int swz=(wl&7)<<4;
  const int o0 = (wl*128 + 16*ag) ^ swz;
  const int o1 = (wl*128 + 64 + 16*ag) ^ swz;
  float hold[8];
  {
    char* Hw=(char*)&hhi[0][grp][0][0];
    char* Lw=(char*)&hlo[0][grp][0][0];
    #pragma unroll
    for (int b=0;b<2;++b){
      const int j0 = 32*hh + 16*b + 4*ag;
      f32x4 hv = *(const f32x4*)&HW[(size_t)v*64 + j0];
      #pragma unroll
      for (int r=0;r<4;++r) hold[4*b+r]=hv[r];
      uint2 whi, wlo;
      pack_hilo(&hold[4*b], &whi, &wlo);
      const int off = (wl*128 + j0*2) ^ swz;
      *(uint2*)(Hw+off)=whi;
      *(uint2*)(Lw+off)=wlo;
    }
  }
  __syncthreads();
  for (int t=0;t<15;++t){
    const int cur = t&1;
    const char* Hb=(const char*)&hhi[cur][grp][0][0];
    const char* Lb=(const char*)&hlo[cur][grp][0][0];
    short8v bh0=*(const short8v*)(Hb+o0), bh1=*(const short8v*)(Hb+o1);
    short8v bl0=*(const short8v*)(Lb+o0), bl1=*(const short8v*)(Lb+o1);
    f32x4 C[6];
    MM6(0,bh0,bh1,bl0,bl1,C[0]); MM6(1,bh0,bh1,bl0,bl1,C[1]);
    MM6(2,bh0,bh1,bl0,bl1,C[2]); MM6(3,bh0,bh1,bl0,bl1,C[3]);
    MM6(4,bh0,bh1,bl0,bl1,C[4]); MM6(5,bh0,bh1,bl0,bl1,C[5]);
    const float* xg;
    if (t&1) xg = E2 + (size_t)eids[v*7+(t>>1)]*192;
    else     xg = XGE + ((size_t)v*8+(t>>1))*192;
    float hnew[8];
    #pragma unroll
    for (int b=0;b<2;++b){
      const int j0 = 32*hh + 16*b + 4*ag;
      f32x4 xr = *(const f32x4*)(xg + j0);
      f32x4 xz = *(const f32x4*)(xg + 64 + j0);
      f32x4 xn = *(const f32x4*)(xg + 128 + j0);
      #pragma unroll
      for (int r=0;r<4;++r){
        float rr=sigm(xr[r]+C[b][r]);
        float zz=sigm(xz[r]+C[2+b][r]);
        float nn=tanh_(xn[r]+rr*(C[4+b][r] + bhhn[4*b+r]));   // bhh_n inside r*()
        hnew[4*b+r]=(1.f-zz)*nn+zz*hold[4*b+r];
      }
    }
    char* Hw=(char*)&hhi[cur^1][grp][0][0];
    char* Lw=(char*)&hlo[cur^1][grp][0][0];
    #pragma unroll
    for (int b=0;b<2;++b){
      const int j0 = 32*hh + 16*b + 4*ag;
      uint2 whi, wlo;
      pack_hilo(&hnew[4*b], &whi, &wlo);
      const int off = (wl*128 + j0*2) ^ swz;
      *(uint2*)(Hw+off)=whi;
      *(uint2*)(Lw+off)=wlo;
    }
    #pragma unroll
    for (int i=0;i<8;++i) hold[i]=hnew[i];
    __syncthreads();
  }
  #pragma unroll
  for (int b=0;b<2;++b){
    const int j0 = 32*hh + 16*b + 4*ag;
    *(f32x4*)&out[(size_t)v*64 + j0] =
      (f32x4){hold[4*b],hold[4*b+1],hold[4*b+2],hold[4*b+3]};
  }
}

#define DOT4(a,b) ((a).x*(b).x+(a).y*(b).y+(a).z*(b).z+(a).w*(b).w)

// in-place projection: XGE row <- A^T yf + B^T yb + H2[node] + dd*wdeg + bias
// bias: bih_m always; bhh_m only rows<128 (n-gate bhh handled in k_main_m)
__global__ __launch_bounds__(512,2) void k_proj(
    const float* __restrict__ WLA, const float* __restrict__ WLB,
    const float* __restrict__ H2, const float* __restrict__ wdeg,
    const float* __restrict__ bihm, const float* __restrict__ bhhm,
    const int* __restrict__ M_node, const float* __restrict__ M_dd,
    float* __restrict__ XGE)
{
  __shared__ __align__(16) float yt[64][132];
  __shared__ float sb_wdeg[192], sb_bihm[192];
  __shared__ int   nd_l[64];
  __shared__ float dd_l[64];

  const int tid=threadIdx.x, wave=tid>>6, lane=tid&63;
  const int wkb=wave<<3;
  const size_t r0 = (size_t)blockIdx.x*64;

  if (tid<192){ sb_wdeg[tid]=wdeg[tid]; sb_bihm[tid]=bihm[tid] + (tid<128? bhhm[tid] : 0.f); }
  for (int i=tid;i<2048;i+=512){
    int row=i>>5, c4=i&31;
    *(float4*)&yt[row][c4*4] = *(const float4*)&XGE[(r0+row)*192 + c4*4];
  }
  if (tid<64){ nd_l[tid]=M_node[r0+tid]; dd_l[tid]=M_dd[r0+tid]; }
  __syncthreads();

  const float4* A4=(const float4*)WLA;
  const float4* B4=(const float4*)WLB;
  float p0[8],p1[8],p2[8];
  #pragma unroll
  for (int w=0;w<8;++w){ p0[w]=0.f;p1[w]=0.f;p2[w]=0.f; }
  #pragma unroll 2
  for (int c=0;c<16;++c){
    float4 wa0=A4[c*192+lane], wa1=A4[c*192+64+lane], wa2=A4[c*192+128+lane];
    float4 wb0=B4[c*192+lane], wb1=B4[c*192+64+lane], wb2=B4[c*192+128+lane];
    #pragma unroll
    for (int w=0;w<8;++w){
      float4 yf=*(const float4*)&yt[wkb+w][c*4];
      float4 yb=*(const float4*)&yt[wkb+w][64+c*4];
      p0[w]+=DOT4(wa0,yf)+DOT4(wb0,yb);
      p1[w]+=DOT4(wa1,yf)+DOT4(wb1,yb);
      p2[w]+=DOT4(wa2,yf)+DOT4(wb2,yb);
    }
  }
  #pragma unroll
  for (int w=0;w<8;++w){
    const size_t row=r0+wkb+w;
    const int nd=nd_l[wkb+w];
    const float dd=dd_l[wkb+w];
    const size_t h2b=(size_t)nd*192;
    XGE[row*192+lane]     = p0[w] + H2[h2b+lane]     + dd*sb_wdeg[lane]     + sb_bihm[lane];
    XGE[row*192+64+lane]  = p1[w] + H2[h2b+64+lane]  + dd*sb_wdeg[64+lane]  + sb_bihm[64+lane];
    XGE[row*192+128+lane] = p2[w] + H2[h2b+128+lane] + dd*sb_wdeg[128+lane] + sb_bihm[128+lane];
  }
}

extern "C" void kernel_launch(void* const* d_in, const int* in_sizes, int n_in,
                              void* d_out, int out_size, void* d_ws, size_t ws_size,
                              hipStream_t stream)
{
  const float* h      = (const float*)d_in[0];
  const float* e      = (const float*)d_in[2];
  const int*   walks  = (const int*)d_in[3];
  const int*   eids   = (const int*)d_in[4];
  const int*   degs   = (const int*)d_in[5];
  const float* wih_wf = (const float*)d_in[6];
  const float* whh_wf = (const float*)d_in[7];
  const float* bih_wf = (const float*)d_in[8];
  const float* bhh_wf = (const float*)d_in[9];
  const float* wih_wb = (const float*)d_in[10];
  const float* whh_wb = (const float*)d_in[11];
  const float* bih_wb = (const float*)d_in[12];
  const float* bhh_wb = (const float*)d_in[13];
  const float* wih_m  = (const float*)d_in[14];
  const float* whh_m  = (const float*)d_in[15];
  const float* bih_m  = (const float*)d_in[16];
  const float* bhh_m  = (const float*)d_in[17];
  const float* w_edge = (const float*)d_in[18];
  float* out = (float*)d_out;
  float* wsf = (float*)d_ws;

  float* WL   = wsf + OFF_WL;
  float* Me   = wsf + OFF_ME;
  float* WmhT = wsf + OFF_WMHT;
  float* wdeg = wsf + OFF_WDEG;
  int*   dmax = (int*)(wsf + OFF_DMAX);
  float* E2   = wsf + OFF_E2;
  float* H2   = wsf + OFF_H2;
  float* XGE  = wsf + OFF_XGE;
  float* HW   = wsf + OFF_HW;
  int*   MND  = (int*)(wsf + OFF_MND);
  float* MDD  = wsf + OFF_MDD;
  float* Tfp  = wsf + OFF_TFP;
  float* Tbp  = wsf + OFF_TBP;
  unsigned short* WB = (unsigned short*)(wsf + OFF_WB);

  hipLaunchKernelGGL(k_init,      dim3(1),    dim3(64), 0, stream, dmax);
  hipLaunchKernelGGL(k_prep_wl,   dim3(96),   dim3(256),0, stream, wih_m, WL);
  hipLaunchKernelGGL(k_prep_wb,   dim3(288),  dim3(256),0, stream, whh_wf,whh_wb,whh_m, WB);
  hipLaunchKernelGGL(k_prep_tblp, dim3(13),   dim3(256),0, stream,
                     wih_wf,bih_wf,bhh_wf, wih_wb,bih_wb,bhh_wb, Tfp,Tbp);
  hipLaunchKernelGGL(k_prep_misc, dim3(61),   dim3(256),0, stream, wih_m,w_edge,Me,WmhT,wdeg);
  hipLaunchKernelGGL(k_degmax,    dim3(1000), dim3(256),0, stream, walks,degs,dmax,HW);
  hipLaunchKernelGGL(k_e2h2,      dim3(NEDGE+NNODE),dim3(192),0, stream,
                     e,Me,bih_m,bhh_m,h,WmhT,E2,H2);
  hipLaunchKernelGGL(k_wgru_m,    dim3(2000), dim3(256),0, stream,
                     walks,degs,dmax, WB, Tfp,Tbp, bhh_wf,bhh_wb, XGE,HW,MND,MDD);
  hipLaunchKernelGGL(k_proj,      dim3(4000), dim3(512),0, stream,
                     WL+3*12288, WL+4*12288, H2, wdeg, bih_m, bhh_m, MND, MDD, XGE);
  hipLaunchKernelGGL(k_main_m,    dim3(1000), dim3(256),0, stream,
                     eids, WB, bhh_m, XGE, E2, HW, out);
  (void)in_sizes;(void)n_in;(void)out_size;(void)ws_size;
}

// Round 15
// 447.940 us; speedup vs baseline: 13.4419x; 1.2748x over previous
//
#include <hip/hip_runtime.h>
#include <math.h>

#define NWALK 32000
#define NNODE 8000
#define NEDGE 64000

typedef __attribute__((ext_vector_type(8))) short short8v;   // 8 bf16 (4 VGPRs)
typedef __attribute__((ext_vector_type(4))) float f32x4;     // MFMA C/D

// workspace layout (float offsets)
static const size_t OFF_WP   = 0;                          // proj A-frags hi/lo: 49152 ushort (24576 f)
static const size_t OFF_ME   = OFF_WP + 5*12288;           // M_edge[192][16]
static const size_t OFF_WMHT = OFF_ME + 3072;              // WmhT[64][192]
static const size_t OFF_WDEG = OFF_WMHT + 12288;           // wdeg[192]
static const size_t OFF_DMAX = OFF_WDEG + 192;             // int degmax (+pad)
static const size_t OFF_E2   = OFF_DMAX + 64;              // E2[64000][192]
static const size_t OFF_H2   = OFF_E2 + (size_t)NEDGE*192; // H2[8000][192]
static const size_t OFF_XGE  = OFF_H2 + (size_t)NNODE*192; // XGE[256000][192]
static const size_t OFF_HW   = OFF_XGE + (size_t)NWALK*8*192; // HW[32000][64]
static const size_t OFF_MND  = OFF_HW + (size_t)NWALK*64;  // M_node[256000] (int)
static const size_t OFF_MDD  = OFF_MND + (size_t)NWALK*8;  // M_dd[256000]
static const size_t OFF_TFP  = OFF_MDD + (size_t)NWALK*8;  // Tf'[8][196] (bih all; bhh folded r,z only)
static const size_t OFF_TBP  = OFF_TFP + 1568;             // Tb'[8][196]
static const size_t OFF_WB   = OFF_TBP + 1568;             // bf16 hi/lo A-frags: 3 mats x 2 hh x 12288 ushort

__device__ __forceinline__ float sigm(float x){ return 1.f/(1.f+__expf(-x)); }
__device__ __forceinline__ float tanh_(float x){ float e=__expf(2.f*x); return 1.f-2.f/(e+1.f); }
__device__ __forceinline__ unsigned short f2bf(float x){
  unsigned u = __float_as_uint(x);
  unsigned r = (u + 0x7FFFu + ((u>>16)&1u)) >> 16;   // RNE
  return (unsigned short)r;
}
__device__ __forceinline__ float bf2f(unsigned short h){
  return __uint_as_float(((unsigned)h)<<16);
}

__global__ void k_init(int* dmax){ if (threadIdx.x==0) *dmax = 0; }

// proj A-frags hi/lo for W' = wih_m[:,64:192] (A|B contiguous), 192x128.
// frag f=a*8+c*2+p (a=row-tile 0..11, c=k-chunk 0..3, p=0 hi/1 lo)
// ushort addr = f*512 + lane*8 + i;  W'[row=16a+(lane&15)][k=32c+8*(lane>>4)+i]
__global__ void k_prep_wp(const float* __restrict__ wih_m, unsigned short* __restrict__ WP){
  int idx = blockIdx.x*256 + threadIdx.x;
  if (idx >= 49152) return;
  int f = idx/512, r3 = idx%512;
  int lane = r3>>3, i = r3&7;
  int a = f>>3, c = (f>>1)&3, p = f&1;
  int row = 16*a + (lane&15);
  int k = 32*c + 8*(lane>>4) + i;
  float val = wih_m[row*193 + 64 + k];
  unsigned short hi = f2bf(val);
  WP[idx] = (p==0) ? hi : f2bf(val - bf2f(hi));
}

// bf16 hi/lo MFMA A-fragments for whh_wf / whh_wb / whh_m, split by hidden-half hh.
__global__ void k_prep_wb(const float* __restrict__ whh_wf, const float* __restrict__ whh_wb,
                          const float* __restrict__ whh_m, unsigned short* __restrict__ WB){
  int idx = blockIdx.x*256+threadIdx.x;
  if (idx >= 3*2*12288) return;
  int mat = idx/24576; int r1 = idx%24576;
  int hh  = r1/12288;  int r2 = r1%12288;
  int f   = r2/512;    int r3 = r2%512;
  int lane= r3>>3, i = r3&7;
  int a = f>>2, c=(f>>1)&1, p=f&1;
  int t = 4*(a>>1) + 2*hh + (a&1);
  int row = 16*t + (lane&15);
  int k = 32*c + 8*(lane>>4) + i;
  const float* W = (mat==0)? whh_wf : ((mat==1)? whh_wb : whh_m);
  float val = W[row*64+k];
  unsigned short hi = f2bf(val);
  WB[idx] = (p==0) ? hi : f2bf(val - bf2f(hi));
}

// padded gate tables (stride 196): bih always; bhh folded ONLY for r,z rows (g<128).
__global__ void k_prep_tblp(const float* __restrict__ wih_wf,const float* __restrict__ bih_wf,
                            const float* __restrict__ bhh_wf,
                            const float* __restrict__ wih_wb,const float* __restrict__ bih_wb,
                            const float* __restrict__ bhh_wb,
                            float* __restrict__ Tfp, float* __restrict__ Tbp){
  int idx = blockIdx.x*256+threadIdx.x;
  if (idx >= 2*1568) return;
  int which = idx/1568, r = idx%1568;
  int u = r/196, g = r%196;
  float val = 0.f;
  if (g < 192){
    float ang = (float)u * 0.78539816339744831f;
    float s = sinf(ang), cc = cosf(ang);
    if (!which) val = bih_wf[g] + wih_wf[g*2]*s + wih_wf[g*2+1]*cc + (g<128? bhh_wf[g] : 0.f);
    else        val = bih_wb[g] + wih_wb[g*2]*s + wih_wb[g*2+1]*cc + (g<128? bhh_wb[g] : 0.f);
  }
  (which? Tbp : Tfp)[u*196+g] = val;
}

__global__ void k_prep_misc(const float* __restrict__ wih_m, const float* __restrict__ w_edge,
                            float* __restrict__ M, float* __restrict__ WmhT,
                            float* __restrict__ wdeg){
  int idx = blockIdx.x*256+threadIdx.x;
  if (idx < 3072){
    int g = idx >> 4, f = idx & 15;
    float acc = 0.f;
    for (int d=0; d<193; ++d) acc += wih_m[g*193+d]*w_edge[d*16+f];
    M[g*16+f] = acc;
  }
  int j = idx - 3072;
  if (j >= 0 && j < 12288){
    int k = j / 192, g = j % 192;
    WmhT[k*192+g] = wih_m[g*193+k];
  }
  int q = idx - 3072 - 12288;
  if (q >= 0 && q < 192) wdeg[q] = wih_m[q*193+192];
}

// degmax reduce + zero HW (atomicAdd accumulation target)
__global__ void k_degmax(const int* __restrict__ walks, const int* __restrict__ degs,
                         int* __restrict__ dmax, float* __restrict__ HW){
  int idx = blockIdx.x*256+threadIdx.x;
  int v = 0;
  if (idx < NWALK*8) v = degs[walks[idx]];
  #pragma unroll
  for (int off=32; off; off>>=1) v = max(v, __shfl_xor(v, off));
  if ((threadIdx.x & 63)==0) atomicMax(dmax, v);
  for (size_t i=idx; i<(size_t)NWALK*64; i+=256000) HW[i]=0.f;
}

// fused: E2 rows (bih_m always; bhh_m folded only g<128) and H2 rows
__global__ void k_e2h2(const float* __restrict__ e, const float* __restrict__ M,
                       const float* __restrict__ bih_m, const float* __restrict__ bhh_m,
                       const float* __restrict__ h, const float* __restrict__ WmhT,
                       float* __restrict__ E2, float* __restrict__ H2){
  const int bx = blockIdx.x;
  const int g = threadIdx.x;
  if (bx < NEDGE){
    __shared__ float ev[16];
    if (g < 16) ev[g] = e[bx*16+g];
    __syncthreads();
    float acc = bih_m[g] + (g<128? bhh_m[g] : 0.f);
    #pragma unroll
    for (int f=0; f<16; ++f) acc += ev[f]*M[g*16+f];
    E2[(size_t)bx*192+g] = acc;
  } else {
    const int node = bx - NEDGE;
    __shared__ float hv[64];
    if (g < 64) hv[g] = h[node*64+g];
    __syncthreads();
    float acc = 0.f;
    for (int k=0;k<64;++k) acc += hv[k]*WmhT[k*192+g];
    H2[(size_t)node*192+g] = acc;
  }
}

// 6 MFMA hi/lo-split matvec chunk for one 16-row tile a:
#define MM6(a, BH0, BH1, BL0, BL1, OUT) do { \
  f32x4 acc_={0.f,0.f,0.f,0.f}; \
  acc_=__builtin_amdgcn_mfma_f32_16x16x32_bf16(afr[(a)*4+0],BH0,acc_,0,0,0); \
  acc_=__builtin_amdgcn_mfma_f32_16x16x32_bf16(afr[(a)*4+2],BH1,acc_,0,0,0); \
  acc_=__builtin_amdgcn_mfma_f32_16x16x32_bf16(afr[(a)*4+0],BL0,acc_,0,0,0); \
  acc_=__builtin_amdgcn_mfma_f32_16x16x32_bf16(afr[(a)*4+2],BL1,acc_,0,0,0); \
  acc_=__builtin_amdgcn_mfma_f32_16x16x32_bf16(afr[(a)*4+1],BH0,acc_,0,0,0); \
  acc_=__builtin_amdgcn_mfma_f32_16x16x32_bf16(afr[(a)*4+3],BH1,acc_,0,0,0); \
  OUT=acc_; \
} while(0)

// pack 4 floats -> hi uint2 + lo uint2 (bf16 split)
__device__ __forceinline__ void pack_hilo(const float* hn, uint2* whi, uint2* wlo){
  unsigned short h0=f2bf(hn[0]), h1=f2bf(hn[1]), h2=f2bf(hn[2]), h3=f2bf(hn[3]);
  whi->x = (unsigned)h0 | ((unsigned)h1<<16);
  whi->y = (unsigned)h2 | ((unsigned)h3<<16);
  unsigned short l0=f2bf(hn[0]-bf2f(h0)), l1=f2bf(hn[1]-bf2f(h1));
  unsigned short l2=f2bf(hn[2]-bf2f(h2)), l3=f2bf(hn[3]-bf2f(h3));
  wlo->x = (unsigned)l0 | ((unsigned)l1<<16);
  wlo->y = (unsigned)l2 | ((unsigned)l3<<16);
}

// ---------------------------------------------------------------------------
// MFMA walk-GRU, hi/lo split (unchanged from R12, verified).
// ---------------------------------------------------------------------------
__global__ __launch_bounds__(256,1) void k_wgru_m(
    const int* __restrict__ walks, const int* __restrict__ degs,
    const int* __restrict__ dmaxp, const unsigned short* __restrict__ WB,
    const float* __restrict__ Tfp, const float* __restrict__ Tbp,
    const float* __restrict__ bhh_f, const float* __restrict__ bhh_b,
    float* __restrict__ XGE, float* __restrict__ HW,
    int* __restrict__ M_node, float* __restrict__ M_dd)
{
  __shared__ float tbl[1568];
  __shared__ int   m_u[32][8];
  __shared__ unsigned short hhi[2][2][16][64];   // [buf][grp][walk][j]
  __shared__ unsigned short hlo[2][2][16][64];
  const int bx=blockIdx.x;
  const int dirb = (bx>=1000);
  const int tid=threadIdx.x, wave=tid>>6, lane=tid&63;
  const int grp=wave>>1, hh=wave&1;
  const int wl=lane&15, ag=lane>>4;
  const int vbase=(dirb?bx-1000:bx)*32;
  const int v = vbase + grp*16 + wl;

  const float* TS = dirb? Tbp : Tfp;
  const float* BH = dirb? bhh_b : bhh_f;
  float bhhn[8];
  #pragma unroll
  for (int b=0;b<2;++b)
    #pragma unroll
    for (int r=0;r<4;++r)
      bhhn[4*b+r] = BH[128 + 32*hh + 16*b + 4*ag + r];   // n-gate hidden bias
  for (int i=tid;i<1568;i+=256) tbl[i]=TS[i];
  if (tid<32){
    const int vv=vbase+tid;
    int w[8];
    #pragma unroll
    for (int i=0;i<8;++i) w[i]=walks[vv*8+i];
    int u[8];
    #pragma unroll
    for (int i=0;i<8;++i){
      int ui=i;
      #pragma unroll
      for (int j=7;j>=0;--j) if (j<=i && w[j]==w[i]) ui=j;   // first occurrence
      u[i]=ui;
    }
    #pragma unroll
    for (int t=0;t<8;++t) m_u[tid][t]=u[7-t];
    if (!dirb){
      const float dmx=(float)(*dmaxp);
      #pragma unroll
      for (int t=0;t<8;++t){
        int nd=w[7-t];
        M_node[(size_t)vv*8+t]=nd;
        M_dd[(size_t)vv*8+t]=(float)degs[nd]/dmx;
      }
    }
  }
  short8v afr[24];
  const short8v* WBv = (const short8v*)(WB + (size_t)(dirb*2+hh)*12288);
  #pragma unroll
  for (int f=0;f<24;++f) afr[f]=WBv[f*64+lane];
  __syncthreads();

  float hold[8];
  #pragma unroll
  for (int i=0;i<8;++i) hold[i]=0.f;
  const int swz = (wl&7)<<4;
  const int ycol = dirb?64:0;
  const int o0 = (wl*128 + 16*ag) ^ swz;        // k-chunk 0 read offset
  const int o1 = (wl*128 + 64 + 16*ag) ^ swz;   // k-chunk 1

  for (int q=0;q<8;++q){
    const int p_ = dirb?7-q:q;
    const int cur = q&1;
    f32x4 C[6];
    if (q){
      const char* Hb=(const char*)&hhi[cur][grp][0][0];
      const char* Lb=(const char*)&hlo[cur][grp][0][0];
      short8v bh0=*(const short8v*)(Hb+o0), bh1=*(const short8v*)(Hb+o1);
      short8v bl0=*(const short8v*)(Lb+o0), bl1=*(const short8v*)(Lb+o1);
      MM6(0,bh0,bh1,bl0,bl1,C[0]); MM6(1,bh0,bh1,bl0,bl1,C[1]);
      MM6(2,bh0,bh1,bl0,bl1,C[2]); MM6(3,bh0,bh1,bl0,bl1,C[3]);
      MM6(4,bh0,bh1,bl0,bl1,C[4]); MM6(5,bh0,bh1,bl0,bl1,C[5]);
    } else {
      #pragma unroll
      for (int a=0;a<6;++a) C[a]=(f32x4){0.f,0.f,0.f,0.f};
    }
    const int u = m_u[grp*16+wl][p_];
    const float* tb = &tbl[u*196];
    float hnew[8];
    #pragma unroll
    for (int b=0;b<2;++b){
      const int j0 = 32*hh + 16*b + 4*ag;
      f32x4 xr = *(const f32x4*)(tb + j0);
      f32x4 xz = *(const f32x4*)(tb + 64 + j0);
      f32x4 xn = *(const f32x4*)(tb + 128 + j0);
      #pragma unroll
      for (int r=0;r<4;++r){
        float rr = sigm(xr[r] + C[b][r]);
        float zz = sigm(xz[r] + C[2+b][r]);
        float nn = tanh_(xn[r] + rr*(C[4+b][r] + bhhn[4*b+r]));   // bhh_n inside r*()
        hnew[4*b+r] = (1.f-zz)*nn + zz*hold[4*b+r];
      }
    }
    char* Hw=(char*)&hhi[cur^1][grp][0][0];
    char* Lw=(char*)&hlo[cur^1][grp][0][0];
    #pragma unroll
    for (int b=0;b<2;++b){
      const int j0 = 32*hh + 16*b + 4*ag;
      *(f32x4*)&XGE[((size_t)v*8+p_)*192 + ycol + j0] =
        (f32x4){hnew[4*b],hnew[4*b+1],hnew[4*b+2],hnew[4*b+3]};
      uint2 whi, wlo;
      pack_hilo(&hnew[4*b], &whi, &wlo);
      const int off = (wl*128 + j0*2) ^ swz;
      *(uint2*)(Hw+off)=whi;
      *(uint2*)(Lw+off)=wlo;
    }
    #pragma unroll
    for (int i=0;i<8;++i) hold[i]=hnew[i];
    __syncthreads();
  }
  #pragma unroll
  for (int b=0;b<2;++b)
    #pragma unroll
    for (int r=0;r<4;++r)
      atomicAdd(&HW[(size_t)v*64 + 32*hh+16*b+4*ag + r], 0.5f*hold[4*b+r]);
}

// MFMA main-GRU, hi/lo split (unchanged from R12, verified).
__global__ __launch_bounds__(256,1) void k_main_m(
    const int* __restrict__ eids, const unsigned short* __restrict__ WB,
    const float* __restrict__ bhh_m,
    const float* __restrict__ XGE, const float* __restrict__ E2,
    const float* __restrict__ HW, float* __restrict__ out)
{
  __shared__ unsigned short hhi[2][2][16][64];
  __shared__ unsigned short hlo[2][2][16][64];
  const int tid=threadIdx.x, wave=tid>>6, lane=tid&63;
  const int grp=wave>>1, hh=wave&1;
  const int wl=lane&15, ag=lane>>4;
  const int v = blockIdx.x*32 + grp*16 + wl;
  float bhhn[8];
  #pragma unroll
  for (int b=0;b<2;++b)
    #pragma unroll
    for (int r=0;r<4;++r)
      bhhn[4*b+r] = bhh_m[128 + 32*hh + 16*b + 4*ag + r];
  short8v afr[24];
  const short8v* WBv = (const short8v*)(WB + (size_t)(2*2+hh)*12288);
  #pragma unroll
  for (int f=0;f<24;++f) afr[f]=WBv[f*64+lane];
  const int swz=(wl&7)<<4;
  const int o0 = (wl*128 + 16*ag) ^ swz;
  const int o1 = (wl*128 + 64 + 16*ag) ^ swz;
  float hold[8];
  {
    char* Hw=(char*)&hhi[0][grp][0][0];
    char* Lw=(char*)&hlo[0][grp][0][0];
    #pragma unroll
    for (int b=0;b<2;++b){
      const int j0 = 32*hh + 16*b + 4*ag;
      f32x4 hv = *(const f32x4*)&HW[(size_t)v*64 + j0];
      #pragma unroll
      for (int r=0;r<4;++r) hold[4*b+r]=hv[r];
      uint2 whi, wlo;
      pack_hilo(&hold[4*b], &whi, &wlo);
      const int off = (wl*128 + j0*2) ^ swz;
      *(uint2*)(Hw+off)=whi;
      *(uint2*)(Lw+off)=wlo;
    }
  }
  __syncthreads();
  for (int t=0;t<15;++t){
    const int cur = t&1;
    const char* Hb=(const char*)&hhi[cur][grp][0][0];
    const char* Lb=(const char*)&hlo[cur][grp][0][0];
    short8v bh0=*(const short8v*)(Hb+o0), bh1=*(const short8v*)(Hb+o1);
    short8v bl0=*(const short8v*)(Lb+o0), bl1=*(const short8v*)(Lb+o1);
    f32x4 C[6];
    MM6(0,bh0,bh1,bl0,bl1,C[0]); MM6(1,bh0,bh1,bl0,bl1,C[1]);
    MM6(2,bh0,bh1,bl0,bl1,C[2]); MM6(3,bh0,bh1,bl0,bl1,C[3]);
    MM6(4,bh0,bh1,bl0,bl1,C[4]); MM6(5,bh0,bh1,bl0,bl1,C[5]);
    const float* xg;
    if (t&1) xg = E2 + (size_t)eids[v*7+(t>>1)]*192;
    else     xg = XGE + ((size_t)v*8+(t>>1))*192;
    float hnew[8];
    #pragma unroll
    for (int b=0;b<2;++b){
      const int j0 = 32*hh + 16*b + 4*ag;
      f32x4 xr = *(const f32x4*)(xg + j0);
      f32x4 xz = *(const f32x4*)(xg + 64 + j0);
      f32x4 xn = *(const f32x4*)(xg + 128 + j0);
      #pragma unroll
      for (int r=0;r<4;++r){
        float rr=sigm(xr[r]+C[b][r]);
        float zz=sigm(xz[r]+C[2+b][r]);
        float nn=tanh_(xn[r]+rr*(C[4+b][r] + bhhn[4*b+r]));   // bhh_n inside r*()
        hnew[4*b+r]=(1.f-zz)*nn+zz*hold[4*b+r];
      }
    }
    char* Hw=(char*)&hhi[cur^1][grp][0][0];
    char* Lw=(char*)&hlo[cur^1][grp][0][0];
    #pragma unroll
    for (int b=0;b<2;++b){
      const int j0 = 32*hh + 16*b + 4*ag;
      uint2 whi, wlo;
      pack_hilo(&hnew[4*b], &whi, &wlo);
      const int off = (wl*128 + j0*2) ^ swz;
      *(uint2*)(Hw+off)=whi;
      *(uint2*)(Lw+off)=wlo;
    }
    #pragma unroll
    for (int i=0;i<8;++i) hold[i]=hnew[i];
    __syncthreads();
  }
  #pragma unroll
  for (int b=0;b<2;++b){
    const int j0 = 32*hh + 16*b + 4*ag;
    *(f32x4*)&out[(size_t)v*64 + j0] =
      (f32x4){hold[4*b],hold[4*b+1],hold[4*b+2],hold[4*b+3]};
  }
}

// ---------------------------------------------------------------------------
// MFMA projection: XGE row <- W'^T [yf;yb] + H2[node] + dd*wdeg + bias.
// y (f32, XGE cols 0:128) staged to swizzled bf16 hi/lo LDS; W' hi/lo A-frags
// streamed from global (L2-resident). 3-term hi/lo math as MM6 (proven).
// Each wave: 16 rows x 192 outputs (12 tiles x 4 k-chunks).
// ---------------------------------------------------------------------------
__global__ __launch_bounds__(256,1) void k_proj_m(
    const unsigned short* __restrict__ WP,
    const float* __restrict__ H2, const float* __restrict__ wdeg,
    const float* __restrict__ bihm, const float* __restrict__ bhhm,
    const int* __restrict__ M_node, const float* __restrict__ M_dd,
    float* __restrict__ XGE)
{
  __shared__ __align__(16) unsigned short yh[8192];   // 64 rows x 128 bf16 (hi)
  __shared__ __align__(16) unsigned short yl[8192];   // (lo)
  __shared__ __align__(16) float sb_bias[192];
  __shared__ __align__(16) float sb_wdeg[192];
  __shared__ int   nd_l[64];
  __shared__ float dd_l[64];

  const int tid=threadIdx.x, wv=tid>>6, lane=tid&63;
  const int wl=lane&15, ag=lane>>4;
  const size_t r0 = (size_t)blockIdx.x*64;

  if (tid<192){ sb_wdeg[tid]=wdeg[tid]; sb_bias[tid]=bihm[tid] + (tid<128? bhhm[tid] : 0.f); }
  if (tid<64){ nd_l[tid]=M_node[r0+tid]; dd_l[tid]=M_dd[r0+tid]; }
  // stage y (cols 0:128) as bf16 hi/lo, XOR-swizzled rows
  for (int i=tid;i<2048;i+=256){
    const int row=i>>5, j0=(i&31)*4;
    f32x4 yv = *(const f32x4*)&XGE[(r0+row)*192 + j0];
    float tmp[4] = {yv[0],yv[1],yv[2],yv[3]};
    uint2 whi, wlo;
    pack_hilo(tmp, &whi, &wlo);
    const int off = (j0*2) ^ ((row&7)<<4);
    *(uint2*)((char*)yh + row*256 + off) = whi;
    *(uint2*)((char*)yl + row*256 + off) = wlo;
  }
  __syncthreads();

  // B-fragments for this lane's row (walk-row wl of wave wv)
  const int swz = (wl&7)<<4;
  const char* Hb = (const char*)yh + (16*wv+wl)*256;
  const char* Lb = (const char*)yl + (16*wv+wl)*256;
  short8v bh[4], bl[4];
  #pragma unroll
  for (int c=0;c<4;++c){
    bh[c] = *(const short8v*)(Hb + ((c*64 + 16*ag) ^ swz));
    bl[c] = *(const short8v*)(Lb + ((c*64 + 16*ag) ^ swz));
  }

  const short8v* WPv = (const short8v*)WP;
  const int   nd = nd_l[16*wv+wl];
  const float dd = dd_l[16*wv+wl];
  const size_t orow = (r0 + 16*wv + wl)*192;
  const size_t h2b  = (size_t)nd*192;

  #pragma unroll 2
  for (int a=0;a<12;++a){
    f32x4 C = {0.f,0.f,0.f,0.f};
    #pragma unroll
    for (int c=0;c<4;++c){
      short8v whi_ = WPv[(a*8+c*2+0)*64 + lane];
      short8v wlo_ = WPv[(a*8+c*2+1)*64 + lane];
      C = __builtin_amdgcn_mfma_f32_16x16x32_bf16(whi_, bh[c], C, 0,0,0);
      C = __builtin_amdgcn_mfma_f32_16x16x32_bf16(whi_, bl[c], C, 0,0,0);
      C = __builtin_amdgcn_mfma_f32_16x16x32_bf16(wlo_, bh[c], C, 0,0,0);
    }
    const int g0 = 16*a + 4*ag;
    f32x4 h2v = *(const f32x4*)&H2[h2b + g0];
    f32x4 wdv = *(const f32x4*)&sb_wdeg[g0];
    f32x4 bv  = *(const f32x4*)&sb_bias[g0];
    f32x4 o;
    #pragma unroll
    for (int r=0;r<4;++r) o[r] = C[r] + h2v[r] + dd*wdv[r] + bv[r];
    *(f32x4*)&XGE[orow + g0] = o;
  }
}

extern "C" void kernel_launch(void* const* d_in, const int* in_sizes, int n_in,
                              void* d_out, int out_size, void* d_ws, size_t ws_size,
                              hipStream_t stream)
{
  const float* h      = (const float*)d_in[0];
  const float* e      = (const float*)d_in[2];
  const int*   walks  = (const int*)d_in[3];
  const int*   eids   = (const int*)d_in[4];
  const int*   degs   = (const int*)d_in[5];
  const float* wih_wf = (const float*)d_in[6];
  const float* whh_wf = (const float*)d_in[7];
  const float* bih_wf = (const float*)d_in[8];
  const float* bhh_wf = (const float*)d_in[9];
  const float* wih_wb = (const float*)d_in[10];
  const float* whh_wb = (const float*)d_in[11];
  const float* bih_wb = (const float*)d_in[12];
  const float* bhh_wb = (const float*)d_in[13];
  const float* wih_m  = (const float*)d_in[14];
  const float* whh_m  = (const float*)d_in[15];
  const float* bih_m  = (const float*)d_in[16];
  const float* bhh_m  = (const float*)d_in[17];
  const float* w_edge = (const float*)d_in[18];
  float* out = (float*)d_out;
  float* wsf = (float*)d_ws;

  unsigned short* WP = (unsigned short*)(wsf + OFF_WP);
  float* Me   = wsf + OFF_ME;
  float* WmhT = wsf + OFF_WMHT;
  float* wdeg = wsf + OFF_WDEG;
  int*   dmax = (int*)(wsf + OFF_DMAX);
  float* E2   = wsf + OFF_E2;
  float* H2   = wsf + OFF_H2;
  float* XGE  = wsf + OFF_XGE;
  float* HW   = wsf + OFF_HW;
  int*   MND  = (int*)(wsf + OFF_MND);
  float* MDD  = wsf + OFF_MDD;
  float* Tfp  = wsf + OFF_TFP;
  float* Tbp  = wsf + OFF_TBP;
  unsigned short* WB = (unsigned short*)(wsf + OFF_WB);

  hipLaunchKernelGGL(k_init,      dim3(1),    dim3(64), 0, stream, dmax);
  hipLaunchKernelGGL(k_prep_wp,   dim3(192),  dim3(256),0, stream, wih_m, WP);
  hipLaunchKernelGGL(k_prep_wb,   dim3(288),  dim3(256),0, stream, whh_wf,whh_wb,whh_m, WB);
  hipLaunchKernelGGL(k_prep_tblp, dim3(13),   dim3(256),0, stream,
                     wih_wf,bih_wf,bhh_wf, wih_wb,bih_wb,bhh_wb, Tfp,Tbp);
  hipLaunchKernelGGL(k_prep_misc, dim3(61),   dim3(256),0, stream, wih_m,w_edge,Me,WmhT,wdeg);
  hipLaunchKernelGGL(k_degmax,    dim3(1000), dim3(256),0, stream, walks,degs,dmax,HW);
  hipLaunchKernelGGL(k_e2h2,      dim3(NEDGE+NNODE),dim3(192),0, stream,
                     e,Me,bih_m,bhh_m,h,WmhT,E2,H2);
  hipLaunchKernelGGL(k_wgru_m,    dim3(2000), dim3(256),0, stream,
                     walks,degs,dmax, WB, Tfp,Tbp, bhh_wf,bhh_wb, XGE,HW,MND,MDD);
  hipLaunchKernelGGL(k_proj_m,    dim3(4000), dim3(256),0, stream,
                     WP, H2, wdeg, bih_m, bhh_m, MND, MDD, XGE);
  hipLaunchKernelGGL(k_main_m,    dim3(1000), dim3(256),0, stream,
                     eids, WB, bhh_m, XGE, E2, HW, out);
  (void)in_sizes;(void)n_in;(void)out_size;(void)ws_size;
}